// Round 15
// baseline (108.049 us; speedup 1.0000x reference)
//
#include <hip/hip_runtime.h>
#include <hip/hip_bf16.h>
#include <hip/hip_fp16.h>
#include <stdint.h>

#define N_   8
#define C_   256
#define H_   64
#define W_   64
#define CO_  256
#define K_   9
#define HO_  64
#define WO_  64
#define CK_  (C_ * K_)    // 2304
#define P_   (HO_ * WO_)  // 4096

#define BN   128          // p per block
#define BK   64           // ck per K-step (2 MFMA K-slices)
#define NT   36           // K-steps: 9 taps x 4 channel-quarters
#define NTHR 1024         // 16 waves = 4 waves/SIMD

typedef __attribute__((ext_vector_type(8))) _Float16 f16x8;
typedef __attribute__((ext_vector_type(4))) float f32x4;

__device__ __forceinline__ unsigned short f2bf(float f) {
    uint32_t u = __builtin_bit_cast(uint32_t, f);
    uint32_t r = (u + 0x7FFFu + ((u >> 16) & 1u)) >> 16;
    return (unsigned short)r;
}
__device__ __forceinline__ float bf2f(unsigned short u) {
    return __builtin_bit_cast(float, (uint32_t)u << 16);
}
__device__ __forceinline__ unsigned short f2h(float f) {
    return __builtin_bit_cast(unsigned short, (_Float16)f);
}

// ================= FAST PATH (needs 17,956,864 B of d_ws) =================

// pre-pass A: x[n][c][hw] f32 -> xT[n][hw][c] f16
__global__ __launch_bounds__(256)
void transpose_x(const float* __restrict__ x, unsigned short* __restrict__ xT) {
    __shared__ float t[64][65];
    const int n  = blockIdx.z;
    const int c0 = blockIdx.y * 64;
    const int h0 = blockIdx.x * 64;
    const int tx = threadIdx.x & 63;
    const int ty = threadIdx.x >> 6;   // 0..3
    const float* xp = x + ((size_t)n * C_ + c0) * P_ + h0;
    #pragma unroll
    for (int i = 0; i < 16; ++i) {
        int c = ty * 16 + i;
        t[c][tx] = xp[(size_t)c * P_ + tx];
    }
    __syncthreads();
    unsigned short* op = xT + ((size_t)n * P_ + h0) * C_ + c0;
    #pragma unroll
    for (int i = 0; i < 16; ++i) {
        int hw = ty * 16 + i;
        op[(size_t)hw * C_ + tx] = f2h(t[tx][hw]);
    }
}

// pre-pass B: weight[co][c][k] f32 -> Wt[co][k][c] f16
__global__ __launch_bounds__(256)
void reorder_w(const float* __restrict__ w, unsigned short* __restrict__ Wt) {
    const int co = blockIdx.x;
    const int c  = threadIdx.x;
    const float* src = w + (size_t)co * CK_ + (size_t)c * K_;
    float v[9];
    #pragma unroll
    for (int k = 0; k < 9; ++k) v[k] = src[k];
    #pragma unroll
    for (int k = 0; k < 9; ++k)
        Wt[(size_t)co * CK_ + k * C_ + c] = f2h(v[k]);
}

// Raw-barrier helper: keeps in-flight vmem loads alive across the barrier
// (__syncthreads would force s_waitcnt vmcnt(0) first).
__device__ __forceinline__ void barrier_lgkm_only() {
    __builtin_amdgcn_sched_barrier(0);
    asm volatile("s_waitcnt lgkmcnt(0)" ::: "memory");
    __builtin_amdgcn_s_barrier();
    __builtin_amdgcn_sched_barrier(0);
}

// packed bilinear combine of one u32 (2 f16 channels) per corner
#define COMB(dst, A, B, Cc, D) do {                                   \
    __half2 _v = __hmul2(W0, __builtin_bit_cast(__half2, (A)));       \
    _v = __hfma2(W1, __builtin_bit_cast(__half2, (B)), _v);           \
    _v = __hfma2(W2, __builtin_bit_cast(__half2, (Cc)), _v);          \
    _v = __hfma2(W3, __builtin_bit_cast(__half2, (D)), _v);           \
    (dst) = __builtin_bit_cast(unsigned, _v); } while (0)

// Round 15: A-operands (weights) DIRECT FROM GLOBAL/L2 — sWs deleted.
// r14 post-mortem: LDS pipe ~2000-3000cy of the 3813cy/iter wall; weight
// path (32KB ds_write + 64KB ds_read per iter) was an LDS round-trip for
// data that is identical across blocks and L2-resident (Wt=1.18MB < 4MB
// per-XCD L2). A-fragments load straight into VGPRs in MFMA layout:
// Wt[(wm+m*16+l15)*CK + ktap*C + c0 + ks*32 + l4*8] (16B/lane). Also
// removes the weight-staging bank conflicts (r14's 2.36M). LDS: 60.4KB.
// Keeps: 1-barrier double-buffer (B tile only), counted prefetch, XOR
// swizzle on B, f16 packed path, 16 waves, XCD-pin, launch_bounds(1024,4).
__global__ __launch_bounds__(NTHR, 4)
void dcn_main(const unsigned short* __restrict__ xT,
              const unsigned short* __restrict__ Wt,
              const float* __restrict__ offset,
              const float* __restrict__ mask,
              float* __restrict__ out) {
    __shared__ uint2 sIdx[BN * K_];               //  9216 B (write-once)
    __shared__ uint4 sWd [BN * K_];               // 18432 B (write-once)
    __shared__ unsigned short sBs[2][BN * BK];    // 32 KB double-buffered -> 60416 B

    const int tid = threadIdx.x;
    // XCD-pin: bid%8 = XCD = batch image; per-XCD set ~3.2MB fits 4MB L2.
    const int bid = blockIdx.x;
    const int n   = bid & 7;
    const int p0  = (bid >> 3) * BN;   // 32 p-tiles per image

    for (int e = tid; e < BN * K_; e += NTHR) {
        int pl = e / K_;
        int k  = e - pl * K_;
        int p  = p0 + pl;
        int ho = p >> 6, wo = p & 63;
        float offy = offset[(size_t)((n * 2 * K_ + 2 * k)     * P_) + p];
        float offx = offset[(size_t)((n * 2 * K_ + 2 * k + 1) * P_) + p];
        float m    = mask  [(size_t)((n * K_ + k) * P_) + p];
        float py = (float)(k / 3 + ho - 1) + offy;
        float px = (float)(k % 3 + wo - 1) + offx;
        float y0f = floorf(py), x0f = floorf(px);
        float ly = py - y0f,   lx = px - x0f;
        int y0 = (int)y0f, x0 = (int)x0f;
        int y1 = y0 + 1,   x1 = x0 + 1;
        bool vy0 = (y0 >= 0) & (y0 < H_);
        bool vy1 = (y1 >= 0) & (y1 < H_);
        bool vx0 = (x0 >= 0) & (x0 < W_);
        bool vx1 = (x1 >= 0) & (x1 < W_);
        float w00 = (1.f - ly) * (1.f - lx) * m * ((vy0 & vx0) ? 1.f : 0.f);
        float w01 = (1.f - ly) * lx         * m * ((vy0 & vx1) ? 1.f : 0.f);
        float w10 = ly * (1.f - lx)         * m * ((vy1 & vx0) ? 1.f : 0.f);
        float w11 = ly * lx                 * m * ((vy1 & vx1) ? 1.f : 0.f);
        unsigned int cy0 = (unsigned)min(max(y0, 0), H_ - 1);
        unsigned int cy1 = (unsigned)min(max(y1, 0), H_ - 1);
        unsigned int cx0 = (unsigned)min(max(x0, 0), W_ - 1);
        unsigned int cx1 = (unsigned)min(max(x1, 0), W_ - 1);
        sIdx[e] = make_uint2((cy0 * W_ + cx0) | ((cy0 * W_ + cx1) << 16),
                             (cy1 * W_ + cx0) | ((cy1 * W_ + cx1) << 16));
        sWd[e] = make_uint4((unsigned)f2h(w00) * 0x10001u,
                            (unsigned)f2h(w01) * 0x10001u,
                            (unsigned)f2h(w10) * 0x10001u,
                            (unsigned)f2h(w11) * 0x10001u);
    }
    __syncthreads();   // params visible before prefetch(0) reads sIdx

    const unsigned short* xTn = xT + (size_t)n * P_ * C_;

    // ---- roles ----
    // sampling: 8 threads per p-row, 8 channels (16B) each
    const int spl = tid >> 3;                 // 0..127
    const int cs  = tid & 7;                  // channel slot (8 f16 = 16B)
    const int boff = spl * 128 + ((cs ^ (spl & 7)) << 4);

    const int lane = tid & 63;
    const int wid  = tid >> 6;                // 0..15
    const int wm   = (wid & 7) * 32;          // 8 co-groups
    const int wp   = (wid >> 3) * 64;         // 2 p-groups
    const int l15  = lane & 15;
    const int l4   = lane >> 4;
    const int slA  = l4 ^ (l15 & 7);          // ks=0 slot; ks=1 -> ^4

    // A-operand global bases (fragment layout: row wm+m*16+l15, col l4*8)
    const unsigned short* wrow0 = Wt + (size_t)(wm      + l15) * CK_ + l4 * 8;
    const unsigned short* wrow1 = Wt + (size_t)(wm + 16 + l15) * CK_ + l4 * 8;

    f32x4 acc[2][4] = {};

    // prefetch registers (one tile ahead, in flight across the barrier)
    uint4 qa, qb, qc, qd;    // 4 corners x 8 f16

#define PREF(TT) {                                                        \
        const int kn  = (TT) >> 2;                                        \
        const int c0n = ((TT) & 3) * 64;                                  \
        uint2 id = sIdx[spl * K_ + kn];                                   \
        const unsigned short* base = xTn + c0n + cs * 8;                  \
        qa = *(const uint4*)(base + ((size_t)(id.x & 0xFFFFu) << 8));     \
        qb = *(const uint4*)(base + ((size_t)(id.x >> 16)     << 8));     \
        qc = *(const uint4*)(base + ((size_t)(id.y & 0xFFFFu) << 8));     \
        qd = *(const uint4*)(base + ((size_t)(id.y >> 16)     << 8));     \
    }

#define STAGE(TT, BB) {                                                   \
        uint4 wv = sWd[spl * K_ + ((TT) >> 2)];                           \
        __half2 W0 = __builtin_bit_cast(__half2, wv.x);                   \
        __half2 W1 = __builtin_bit_cast(__half2, wv.y);                   \
        __half2 W2 = __builtin_bit_cast(__half2, wv.z);                   \
        __half2 W3 = __builtin_bit_cast(__half2, wv.w);                   \
        uint4 r;                                                          \
        COMB(r.x, qa.x, qb.x, qc.x, qd.x);                                \
        COMB(r.y, qa.y, qb.y, qc.y, qd.y);                                \
        COMB(r.z, qa.z, qb.z, qc.z, qd.z);                                \
        COMB(r.w, qa.w, qb.w, qc.w, qd.w);                                \
        *(uint4*)((char*)(BB) + boff) = r;                                \
    }

    // ---- prologue: tile 0 -> regs -> buf0; tile 1 -> regs ----
    PREF(0)
    STAGE(0, sBs[0])
    PREF(1)

    for (int t = 0; t < NT; ++t) {
        const int br = t & 1;
        const char* bR = (const char*)sBs[br];
        const int kofs = (t >> 2) * C_ + (t & 3) * 64;   // ktap*C + c0

        // single barrier: buf[br] writes (last iter) visible; buf[br^1] reads
        // (last iter's MFMA) complete. In-flight global loads survive.
        barrier_lgkm_only();

        // A-fragments direct from global/L2 (issued first; land under the
        // B-frag LDS reads + stage below)
        f16x8 A00 = *(const f16x8*)(wrow0 + kofs);        // m=0, ks=0
        f16x8 A10 = *(const f16x8*)(wrow1 + kofs);        // m=1, ks=0
        f16x8 A01 = *(const f16x8*)(wrow0 + kofs + 32);   // m=0, ks=1
        f16x8 A11 = *(const f16x8*)(wrow1 + kofs + 32);   // m=1, ks=1

        // ks=0 B-fragment reads
        f16x8 B0, B1, B2, B3;
        {
            const int sl = slA;
            B0 = *(const f16x8*)(bR + (wp      + l15) * 128 + (sl << 4));
            B1 = *(const f16x8*)(bR + (wp + 16 + l15) * 128 + (sl << 4));
            B2 = *(const f16x8*)(bR + (wp + 32 + l15) * 128 + (sl << 4));
            B3 = *(const f16x8*)(bR + (wp + 48 + l15) * 128 + (sl << 4));
        }

        // stage tile t+1 into the write buffer (different buffer -> no
        // second barrier); then issue tile t+2's gathers
        if (t + 1 < NT) {
            if (br) { STAGE(t + 1, sBs[0]) }
            else    { STAGE(t + 1, sBs[1]) }
            if (t + 2 < NT) PREF(t + 2)
        }

        // MFMA ks=0 (co-schedules with the ds_writes above)
        acc[0][0] = __builtin_amdgcn_mfma_f32_16x16x32_f16(A00, B0, acc[0][0], 0, 0, 0);
        acc[0][1] = __builtin_amdgcn_mfma_f32_16x16x32_f16(A00, B1, acc[0][1], 0, 0, 0);
        acc[0][2] = __builtin_amdgcn_mfma_f32_16x16x32_f16(A00, B2, acc[0][2], 0, 0, 0);
        acc[0][3] = __builtin_amdgcn_mfma_f32_16x16x32_f16(A00, B3, acc[0][3], 0, 0, 0);
        acc[1][0] = __builtin_amdgcn_mfma_f32_16x16x32_f16(A10, B0, acc[1][0], 0, 0, 0);
        acc[1][1] = __builtin_amdgcn_mfma_f32_16x16x32_f16(A10, B1, acc[1][1], 0, 0, 0);
        acc[1][2] = __builtin_amdgcn_mfma_f32_16x16x32_f16(A10, B2, acc[1][2], 0, 0, 0);
        acc[1][3] = __builtin_amdgcn_mfma_f32_16x16x32_f16(A10, B3, acc[1][3], 0, 0, 0);

        // ks=1 B-fragment reads + MFMA
        {
            const int sl = slA ^ 4;
            B0 = *(const f16x8*)(bR + (wp      + l15) * 128 + (sl << 4));
            B1 = *(const f16x8*)(bR + (wp + 16 + l15) * 128 + (sl << 4));
            B2 = *(const f16x8*)(bR + (wp + 32 + l15) * 128 + (sl << 4));
            B3 = *(const f16x8*)(bR + (wp + 48 + l15) * 128 + (sl << 4));
        }
        acc[0][0] = __builtin_amdgcn_mfma_f32_16x16x32_f16(A01, B0, acc[0][0], 0, 0, 0);
        acc[0][1] = __builtin_amdgcn_mfma_f32_16x16x32_f16(A01, B1, acc[0][1], 0, 0, 0);
        acc[0][2] = __builtin_amdgcn_mfma_f32_16x16x32_f16(A01, B2, acc[0][2], 0, 0, 0);
        acc[0][3] = __builtin_amdgcn_mfma_f32_16x16x32_f16(A01, B3, acc[0][3], 0, 0, 0);
        acc[1][0] = __builtin_amdgcn_mfma_f32_16x16x32_f16(A11, B0, acc[1][0], 0, 0, 0);
        acc[1][1] = __builtin_amdgcn_mfma_f32_16x16x32_f16(A11, B1, acc[1][1], 0, 0, 0);
        acc[1][2] = __builtin_amdgcn_mfma_f32_16x16x32_f16(A11, B2, acc[1][2], 0, 0, 0);
        acc[1][3] = __builtin_amdgcn_mfma_f32_16x16x32_f16(A11, B3, acc[1][3], 0, 0, 0);
    }
#undef PREF
#undef STAGE

    float* outn = out + (size_t)n * CO_ * P_;
    #pragma unroll
    for (int m = 0; m < 2; ++m) {
        int co = wm + m * 16 + l4 * 4;
        #pragma unroll
        for (int nn = 0; nn < 4; ++nn) {
            int p = p0 + wp + nn * 16 + l15;
            #pragma unroll
            for (int r = 0; r < 4; ++r) {
                outn[(size_t)(co + r) * P_ + p] = acc[m][nn][r];
            }
        }
    }
}

// ================= FALLBACK (round-2 kernel, zero scratch, proven pass) =================
template <int TAG>
__global__ __launch_bounds__(512, 2)
void dcn_fb(const float* __restrict__ x,
            const float* __restrict__ offset,
            const float* __restrict__ mask,
            const float* __restrict__ weight,
            float* __restrict__ out) {
    typedef __attribute__((ext_vector_type(8))) short bf16x8;
    __shared__ uint2  sIdx[128 * K_];
    __shared__ float4 sW  [128 * K_];
    __shared__ unsigned short sWs[CO_ * 32];
    __shared__ unsigned short sBs[128 * 32];

    const int tid = threadIdx.x;
    const int n  = blockIdx.y;
    const int p0 = blockIdx.x * 128;

    for (int e = tid; e < 128 * K_; e += 512) {
        int pl = e / K_;
        int k  = e - pl * K_;
        int p  = p0 + pl;
        int ho = p >> 6, wo = p & 63;
        float offy = offset[(size_t)((n * 2 * K_ + 2 * k)     * P_) + p];
        float offx = offset[(size_t)((n * 2 * K_ + 2 * k + 1) * P_) + p];
        float m    = mask  [(size_t)((n * K_ + k) * P_) + p];
        float py = (float)(k / 3 + ho - 1) + offy;
        float px = (float)(k % 3 + wo - 1) + offx;
        float y0f = floorf(py), x0f = floorf(px);
        float ly = py - y0f,   lx = px - x0f;
        int y0 = (int)y0f, x0 = (int)x0f;
        int y1 = y0 + 1,   x1 = x0 + 1;
        bool vy0 = (y0 >= 0) & (y0 < H_);
        bool vy1 = (y1 >= 0) & (y1 < H_);
        bool vx0 = (x0 >= 0) & (x0 < W_);
        bool vx1 = (x1 >= 0) & (x1 < W_);
        float w00 = (1.f - ly) * (1.f - lx) * m * ((vy0 & vx0) ? 1.f : 0.f);
        float w01 = (1.f - ly) * lx         * m * ((vy0 & vx1) ? 1.f : 0.f);
        float w10 = ly * (1.f - lx)         * m * ((vy1 & vx0) ? 1.f : 0.f);
        float w11 = ly * lx                 * m * ((vy1 & vx1) ? 1.f : 0.f);
        unsigned int cy0 = (unsigned)min(max(y0, 0), H_ - 1);
        unsigned int cy1 = (unsigned)min(max(y1, 0), H_ - 1);
        unsigned int cx0 = (unsigned)min(max(x0, 0), W_ - 1);
        unsigned int cx1 = (unsigned)min(max(x1, 0), W_ - 1);
        sIdx[e] = make_uint2((cy0 * W_ + cx0) | ((cy0 * W_ + cx1) << 16),
                             (cy1 * W_ + cx0) | ((cy1 * W_ + cx1) << 16));
        sW[e]   = make_float4(w00, w01, w10, w11);
    }

    const float* xn = x + (size_t)n * C_ * P_;
    const int pl   = tid >> 2;
    const int pl9  = pl * K_;
    const int ckb  = (tid & 3) * 8;
    const int wco  = tid >> 1;
    const int wck  = (tid & 1) * 16;

    const int lane = tid & 63;
    const int wid  = tid >> 6;
    const int wm   = (wid & 1) * 128;
    const int wp   = (wid >> 1) * 32;
    const int l15  = lane & 15;
    const int l4   = lane >> 4;

    f32x4 acc[8][2] = {};

    for (int ck0 = 0; ck0 < CK_; ck0 += 32) {
        __syncthreads();
        {
            const float4* wsrc = (const float4*)(weight + (size_t)wco * CK_ + ck0 + wck);
            float4 wa = wsrc[0], wb = wsrc[1], wc = wsrc[2], wd = wsrc[3];
            uint4 q0, q1;
            q0.x = f2bf(wa.x) | ((unsigned)f2bf(wa.y) << 16);
            q0.y = f2bf(wa.z) | ((unsigned)f2bf(wa.w) << 16);
            q0.z = f2bf(wb.x) | ((unsigned)f2bf(wb.y) << 16);
            q0.w = f2bf(wb.z) | ((unsigned)f2bf(wb.w) << 16);
            q1.x = f2bf(wc.x) | ((unsigned)f2bf(wc.y) << 16);
            q1.y = f2bf(wc.z) | ((unsigned)f2bf(wc.w) << 16);
            q1.z = f2bf(wd.x) | ((unsigned)f2bf(wd.y) << 16);
            q1.w = f2bf(wd.z) | ((unsigned)f2bf(wd.w) << 16);
            *(uint4*)&sWs[wco * 32 + wck]     = q0;
            *(uint4*)&sWs[wco * 32 + wck + 8] = q1;
        }
        {
            int ckstart = ck0 + ckb;
            int cc = ckstart / 9;
            int kk = ckstart - cc * 9;
            unsigned int packed[4];
            unsigned short colv[8];
            #pragma unroll
            for (int j = 0; j < 8; ++j) {
                int e = pl9 + kk;
                uint2  id = sIdx[e];
                float4 wv = sW[e];
                const float* xp = xn + ((size_t)cc << 12);
                float v = wv.x * xp[id.x & 0xFFFFu]
                        + wv.y * xp[id.x >> 16]
                        + wv.z * xp[id.y & 0xFFFFu]
                        + wv.w * xp[id.y >> 16];
                colv[j] = f2bf(v);
                ++kk; if (kk == 9) { kk = 0; ++cc; }
            }
            packed[0] = colv[0] | ((unsigned)colv[1] << 16);
            packed[1] = colv[2] | ((unsigned)colv[3] << 16);
            packed[2] = colv[4] | ((unsigned)colv[5] << 16);
            packed[3] = colv[6] | ((unsigned)colv[7] << 16);
            *(uint4*)&sBs[pl * 32 + ckb] = *(uint4*)packed;
        }
        __syncthreads();
        bf16x8 bfr0 = *(const bf16x8*)&sBs[(wp + l15)      * 32 + l4 * 8];
        bf16x8 bfr1 = *(const bf16x8*)&sBs[(wp + 16 + l15) * 32 + l4 * 8];
        #pragma unroll
        for (int m = 0; m < 8; ++m) {
            bf16x8 afr = *(const bf16x8*)&sWs[(wm + m * 16 + l15) * 32 + l4 * 8];
            acc[m][0] = __builtin_amdgcn_mfma_f32_16x16x32_bf16(afr, bfr0, acc[m][0], 0, 0, 0);
            acc[m][1] = __builtin_amdgcn_mfma_f32_16x16x32_bf16(afr, bfr1, acc[m][1], 0, 0, 0);
        }
    }

    float* outn = out + (size_t)n * CO_ * P_;
    #pragma unroll
    for (int m = 0; m < 8; ++m) {
        int co = wm + m * 16 + l4 * 4;
        #pragma unroll
        for (int nn = 0; nn < 2; ++nn) {
            int p = p0 + wp + nn * 16 + l15;
            #pragma unroll
            for (int r = 0; r < 4; ++r) {
                outn[(size_t)(co + r) * P_ + p] = acc[m][nn][r];
            }
        }
    }
}

extern "C" void kernel_launch(void* const* d_in, const int* in_sizes, int n_in,
                              void* d_out, int out_size, void* d_ws, size_t ws_size,
                              hipStream_t stream) {
    const float* x      = (const float*)d_in[0];
    const float* offset = (const float*)d_in[1];
    const float* mask   = (const float*)d_in[2];
    const float* weight = (const float*)d_in[3];
    float* out = (float*)d_out;

    const size_t xT_elems = (size_t)N_ * P_ * C_;            // 8,388,608 ushort
    const size_t Wt_elems = (size_t)CO_ * CK_;               //   589,824 ushort
    const size_t need     = (xT_elems + Wt_elems) * sizeof(unsigned short); // 17,956,864 B

    if (ws_size >= need) {
        unsigned short* xT = (unsigned short*)d_ws;
        unsigned short* Wt = xT + xT_elems;
        transpose_x<<<dim3(P_ / 64, C_ / 64, N_), dim3(256), 0, stream>>>(x, xT);
        reorder_w<<<dim3(CO_), dim3(256), 0, stream>>>(weight, Wt);
        // grid: 8 n (XCD-pin) x 32 p-tiles = 256 blocks = 1 block/CU, 16 waves
        dcn_main<<<dim3((P_ / BN) * N_), dim3(NTHR), 0, stream>>>(xT, Wt, offset, mask, out);
    } else if (ws_size >= (8u << 20)) {
        dcn_fb<1><<<dim3(P_ / 128, N_), dim3(512), 0, stream>>>(x, offset, mask, weight, out);
    } else {
        dcn_fb<0><<<dim3(P_ / 128, N_), dim3(512), 0, stream>>>(x, offset, mask, weight, out);
    }
}

// Round 16
// 71.457 us; speedup vs baseline: 1.5121x; 1.5121x over previous
//
#include <hip/hip_runtime.h>
#include <hip/hip_bf16.h>
#include <hip/hip_fp16.h>
#include <stdint.h>

#define N_   8
#define C_   256
#define H_   64
#define W_   64
#define CO_  256
#define K_   9
#define HO_  64
#define WO_  64
#define CK_  (C_ * K_)    // 2304
#define P_   (HO_ * WO_)  // 4096

#define BN   128          // p per block
#define BK   64           // ck per K-step (2 MFMA K-slices)
#define NT   36           // K-steps: 9 taps x 4 channel-quarters
#define NTHR 1024         // 16 waves = 4 waves/SIMD

typedef __attribute__((ext_vector_type(8))) _Float16 f16x8;
typedef __attribute__((ext_vector_type(4))) float f32x4;

__device__ __forceinline__ unsigned short f2bf(float f) {
    uint32_t u = __builtin_bit_cast(uint32_t, f);
    uint32_t r = (u + 0x7FFFu + ((u >> 16) & 1u)) >> 16;
    return (unsigned short)r;
}
__device__ __forceinline__ float bf2f(unsigned short u) {
    return __builtin_bit_cast(float, (uint32_t)u << 16);
}
__device__ __forceinline__ unsigned short f2h(float f) {
    return __builtin_bit_cast(unsigned short, (_Float16)f);
}

// ================= FAST PATH (needs 17,956,864 B of d_ws) =================

// pre-pass A: x[n][c][hw] f32 -> xT[n][hw][c] f16
__global__ __launch_bounds__(256)
void transpose_x(const float* __restrict__ x, unsigned short* __restrict__ xT) {
    __shared__ float t[64][65];
    const int n  = blockIdx.z;
    const int c0 = blockIdx.y * 64;
    const int h0 = blockIdx.x * 64;
    const int tx = threadIdx.x & 63;
    const int ty = threadIdx.x >> 6;   // 0..3
    const float* xp = x + ((size_t)n * C_ + c0) * P_ + h0;
    #pragma unroll
    for (int i = 0; i < 16; ++i) {
        int c = ty * 16 + i;
        t[c][tx] = xp[(size_t)c * P_ + tx];
    }
    __syncthreads();
    unsigned short* op = xT + ((size_t)n * P_ + h0) * C_ + c0;
    #pragma unroll
    for (int i = 0; i < 16; ++i) {
        int hw = ty * 16 + i;
        op[(size_t)hw * C_ + tx] = f2h(t[tx][hw]);
    }
}

// pre-pass B: weight[co][c][k] f32 -> Wt[co][k][c] f16
__global__ __launch_bounds__(256)
void reorder_w(const float* __restrict__ w, unsigned short* __restrict__ Wt) {
    const int co = blockIdx.x;
    const int c  = threadIdx.x;
    const float* src = w + (size_t)co * CK_ + (size_t)c * K_;
    float v[9];
    #pragma unroll
    for (int k = 0; k < 9; ++k) v[k] = src[k];
    #pragma unroll
    for (int k = 0; k < 9; ++k)
        Wt[(size_t)co * CK_ + k * C_ + c] = f2h(v[k]);
}

// Raw-barrier helper: keeps in-flight vmem loads alive across the barrier
// (__syncthreads would force s_waitcnt vmcnt(0) first).
__device__ __forceinline__ void barrier_lgkm_only() {
    __builtin_amdgcn_sched_barrier(0);
    asm volatile("s_waitcnt lgkmcnt(0)" ::: "memory");
    __builtin_amdgcn_s_barrier();
    __builtin_amdgcn_sched_barrier(0);
}

// packed bilinear combine of one u32 (2 f16 channels) per corner
#define COMB(dst, A, B, Cc, D) do {                                   \
    __half2 _v = __hmul2(W0, __builtin_bit_cast(__half2, (A)));       \
    _v = __hfma2(W1, __builtin_bit_cast(__half2, (B)), _v);           \
    _v = __hfma2(W2, __builtin_bit_cast(__half2, (Cc)), _v);          \
    _v = __hfma2(W3, __builtin_bit_cast(__half2, (D)), _v);           \
    (dst) = __builtin_bit_cast(unsigned, _v); } while (0)

// Round 16: r14 base (LDS-staged A, 1-barrier double-buffer, 16 waves)
// + KS-SPLIT: waves 0-7 compute only ks=0, waves 8-15 only ks=1, each
// group tiling the full 256x128 with 64x64 wave tiles (acc[4][4]).
// Per-iter frag reads drop 192 -> 128 b128 wave-ops (B-frag duplication
// 8x -> 4x); LDS pipe was r14's limiter (~2760cy of 3813cy/iter).
// Epilogue: group-1 partials summed into group-0 via 32KB LDS chunks.
// r15 lesson: A-frags from global are uncoalesced (stride-CK rows) ->
// L2-request-rate-bound; LDS staging restored.
__global__ __launch_bounds__(NTHR, 4)
void dcn_main(const unsigned short* __restrict__ xT,
              const unsigned short* __restrict__ Wt,
              const float* __restrict__ offset,
              const float* __restrict__ mask,
              float* __restrict__ out) {
    __shared__ uint2 sIdx[BN * K_];               //  9216 B (write-once)
    __shared__ uint4 sWd [BN * K_];               // 18432 B (write-once)
    __shared__ unsigned short sWs[2][CO_ * BK];   // 64 KB double-buffered
    __shared__ unsigned short sBs[2][BN * BK];    // 32 KB double-buffered -> 125952 B

    const int tid = threadIdx.x;
    // XCD-pin: bid%8 = XCD = batch image; per-XCD set ~3.2MB fits 4MB L2.
    const int bid = blockIdx.x;
    const int n   = bid & 7;
    const int p0  = (bid >> 3) * BN;   // 32 p-tiles per image

    for (int e = tid; e < BN * K_; e += NTHR) {
        int pl = e / K_;
        int k  = e - pl * K_;
        int p  = p0 + pl;
        int ho = p >> 6, wo = p & 63;
        float offy = offset[(size_t)((n * 2 * K_ + 2 * k)     * P_) + p];
        float offx = offset[(size_t)((n * 2 * K_ + 2 * k + 1) * P_) + p];
        float m    = mask  [(size_t)((n * K_ + k) * P_) + p];
        float py = (float)(k / 3 + ho - 1) + offy;
        float px = (float)(k % 3 + wo - 1) + offx;
        float y0f = floorf(py), x0f = floorf(px);
        float ly = py - y0f,   lx = px - x0f;
        int y0 = (int)y0f, x0 = (int)x0f;
        int y1 = y0 + 1,   x1 = x0 + 1;
        bool vy0 = (y0 >= 0) & (y0 < H_);
        bool vy1 = (y1 >= 0) & (y1 < H_);
        bool vx0 = (x0 >= 0) & (x0 < W_);
        bool vx1 = (x1 >= 0) & (x1 < W_);
        float w00 = (1.f - ly) * (1.f - lx) * m * ((vy0 & vx0) ? 1.f : 0.f);
        float w01 = (1.f - ly) * lx         * m * ((vy0 & vx1) ? 1.f : 0.f);
        float w10 = ly * (1.f - lx)         * m * ((vy1 & vx0) ? 1.f : 0.f);
        float w11 = ly * lx                 * m * ((vy1 & vx1) ? 1.f : 0.f);
        unsigned int cy0 = (unsigned)min(max(y0, 0), H_ - 1);
        unsigned int cy1 = (unsigned)min(max(y1, 0), H_ - 1);
        unsigned int cx0 = (unsigned)min(max(x0, 0), W_ - 1);
        unsigned int cx1 = (unsigned)min(max(x1, 0), W_ - 1);
        sIdx[e] = make_uint2((cy0 * W_ + cx0) | ((cy0 * W_ + cx1) << 16),
                             (cy1 * W_ + cx0) | ((cy1 * W_ + cx1) << 16));
        sWd[e] = make_uint4((unsigned)f2h(w00) * 0x10001u,
                            (unsigned)f2h(w01) * 0x10001u,
                            (unsigned)f2h(w10) * 0x10001u,
                            (unsigned)f2h(w11) * 0x10001u);
    }
    __syncthreads();   // params visible before prefetch(0) reads sIdx

    const unsigned short* xTn = xT + (size_t)n * P_ * C_;

    // ---- staging roles (all 1024 threads, unchanged from r14) ----
    const int spl = tid >> 3;                 // 0..127
    const int cs  = tid & 7;                  // channel slot (8 f16 = 16B)
    const int boff = spl * 128 + ((cs ^ (spl & 7)) << 4);
    const int wco  = tid >> 2;                // 0..255
    const int wsl  = tid & 3;                 // slots wsl and wsl+4
    const int wswz = wco & 7;
    const int woff = wco * 128;
    const unsigned short* wsrcbase = Wt + (size_t)wco * CK_ + wsl * 8;

    // ---- compute roles: ks-split wave groups ----
    const int lane = tid & 63;
    const int wid  = tid >> 6;                // 0..15
    const int g    = wid >> 3;                // 0: ks=0, 1: ks=1
    const int w8   = wid & 7;
    const int wm4  = (w8 & 3) * 64;           // 4 co-groups of 64
    const int wp2  = (w8 >> 2) * 64;          // 2 p-groups of 64
    const int l15  = lane & 15;
    const int l4   = lane >> 4;
    const int slG  = (l4 ^ (l15 & 7)) ^ (g << 2);   // this group's K-slice slot

    f32x4 acc[4][4] = {};

    // prefetch registers (one tile ahead, in flight across the barrier)
    uint4 qa, qb, qc, qd;    // 4 corners x 8 f16
    uint4 wq0, wq1;          // 2x 16B of weight row

#define PREF(TT) {                                                        \
        const int kn  = (TT) >> 2;                                        \
        const int c0n = ((TT) & 3) * 64;                                  \
        const unsigned short* ws = wsrcbase + kn * C_ + c0n;              \
        wq0 = *(const uint4*)(ws);                                        \
        wq1 = *(const uint4*)(ws + 32);                                   \
        uint2 id = sIdx[spl * K_ + kn];                                   \
        const unsigned short* base = xTn + c0n + cs * 8;                  \
        qa = *(const uint4*)(base + ((size_t)(id.x & 0xFFFFu) << 8));     \
        qb = *(const uint4*)(base + ((size_t)(id.x >> 16)     << 8));     \
        qc = *(const uint4*)(base + ((size_t)(id.y & 0xFFFFu) << 8));     \
        qd = *(const uint4*)(base + ((size_t)(id.y >> 16)     << 8));     \
    }

#define STAGE(TT, WB, BB) {                                               \
        char* wrB = (char*)(WB) + woff;                                   \
        *(uint4*)(wrB + ((wsl       ^ wswz) << 4)) = wq0;                 \
        *(uint4*)(wrB + (((wsl + 4) ^ wswz) << 4)) = wq1;                 \
        uint4 wv = sWd[spl * K_ + ((TT) >> 2)];                           \
        __half2 W0 = __builtin_bit_cast(__half2, wv.x);                   \
        __half2 W1 = __builtin_bit_cast(__half2, wv.y);                   \
        __half2 W2 = __builtin_bit_cast(__half2, wv.z);                   \
        __half2 W3 = __builtin_bit_cast(__half2, wv.w);                   \
        uint4 r;                                                          \
        COMB(r.x, qa.x, qb.x, qc.x, qd.x);                                \
        COMB(r.y, qa.y, qb.y, qc.y, qd.y);                                \
        COMB(r.z, qa.z, qb.z, qc.z, qd.z);                                \
        COMB(r.w, qa.w, qb.w, qc.w, qd.w);                                \
        *(uint4*)((char*)(BB) + boff) = r;                                \
    }

    // ---- prologue: tile 0 -> regs -> buf0; tile 1 -> regs ----
    PREF(0)
    STAGE(0, sWs[0], sBs[0])
    PREF(1)

    for (int t = 0; t < NT; ++t) {
        const int br = t & 1;
        const char* wR = (const char*)sWs[br];
        const char* bR = (const char*)sBs[br];

        // single barrier: buf[br] writes (last iter) visible; buf[br^1]
        // reads (last iter's MFMA) done. In-flight global loads survive.
        barrier_lgkm_only();

        // B-fragments for this group's K-slice (4 x b128)
        f16x8 B0 = *(const f16x8*)(bR + (wp2      + l15) * 128 + (slG << 4));
        f16x8 B1 = *(const f16x8*)(bR + (wp2 + 16 + l15) * 128 + (slG << 4));
        f16x8 B2 = *(const f16x8*)(bR + (wp2 + 32 + l15) * 128 + (slG << 4));
        f16x8 B3 = *(const f16x8*)(bR + (wp2 + 48 + l15) * 128 + (slG << 4));

        // stage tile t+1 into the other buffer; issue t+2's gathers
        if (t + 1 < NT) {
            if (br) { STAGE(t + 1, sWs[0], sBs[0]) }
            else    { STAGE(t + 1, sWs[1], sBs[1]) }
            if (t + 2 < NT) PREF(t + 2)
        }

        // A-fragments incrementally + MFMA (1 ks per group, 4x4 frags)
        #pragma unroll
        for (int mf = 0; mf < 4; ++mf) {
            f16x8 A = *(const f16x8*)(wR + (wm4 + mf * 16 + l15) * 128 + (slG << 4));
            acc[mf][0] = __builtin_amdgcn_mfma_f32_16x16x32_f16(A, B0, acc[mf][0], 0, 0, 0);
            acc[mf][1] = __builtin_amdgcn_mfma_f32_16x16x32_f16(A, B1, acc[mf][1], 0, 0, 0);
            acc[mf][2] = __builtin_amdgcn_mfma_f32_16x16x32_f16(A, B2, acc[mf][2], 0, 0, 0);
            acc[mf][3] = __builtin_amdgcn_mfma_f32_16x16x32_f16(A, B3, acc[mf][3], 0, 0, 0);
        }
    }
#undef PREF
#undef STAGE

    // ---- epilogue: reduce ks=1 partials into ks=0 waves via LDS ----
    f32x4* red = (f32x4*)sWs;                 // reuse 32KB of staging LDS
    const int ridx = (w8 * 64 + lane) * 4;
    #pragma unroll
    for (int mf = 0; mf < 4; ++mf) {
        __syncthreads();
        if (g == 1) {
            red[ridx + 0] = acc[mf][0];
            red[ridx + 1] = acc[mf][1];
            red[ridx + 2] = acc[mf][2];
            red[ridx + 3] = acc[mf][3];
        }
        __syncthreads();
        if (g == 0) {
            acc[mf][0] += red[ridx + 0];
            acc[mf][1] += red[ridx + 1];
            acc[mf][2] += red[ridx + 2];
            acc[mf][3] += red[ridx + 3];
        }
    }

    if (g == 0) {
        float* outn = out + (size_t)n * CO_ * P_;
        #pragma unroll
        for (int mf = 0; mf < 4; ++mf) {
            int co = wm4 + mf * 16 + l4 * 4;
            #pragma unroll
            for (int nn = 0; nn < 4; ++nn) {
                int p = p0 + wp2 + nn * 16 + l15;
                #pragma unroll
                for (int r = 0; r < 4; ++r) {
                    outn[(size_t)(co + r) * P_ + p] = acc[mf][nn][r];
                }
            }
        }
    }
}

// ================= FALLBACK (round-2 kernel, zero scratch, proven pass) =================
template <int TAG>
__global__ __launch_bounds__(512, 2)
void dcn_fb(const float* __restrict__ x,
            const float* __restrict__ offset,
            const float* __restrict__ mask,
            const float* __restrict__ weight,
            float* __restrict__ out) {
    typedef __attribute__((ext_vector_type(8))) short bf16x8;
    __shared__ uint2  sIdx[128 * K_];
    __shared__ float4 sW  [128 * K_];
    __shared__ unsigned short sWs[CO_ * 32];
    __shared__ unsigned short sBs[128 * 32];

    const int tid = threadIdx.x;
    const int n  = blockIdx.y;
    const int p0 = blockIdx.x * 128;

    for (int e = tid; e < 128 * K_; e += 512) {
        int pl = e / K_;
        int k  = e - pl * K_;
        int p  = p0 + pl;
        int ho = p >> 6, wo = p & 63;
        float offy = offset[(size_t)((n * 2 * K_ + 2 * k)     * P_) + p];
        float offx = offset[(size_t)((n * 2 * K_ + 2 * k + 1) * P_) + p];
        float m    = mask  [(size_t)((n * K_ + k) * P_) + p];
        float py = (float)(k / 3 + ho - 1) + offy;
        float px = (float)(k % 3 + wo - 1) + offx;
        float y0f = floorf(py), x0f = floorf(px);
        float ly = py - y0f,   lx = px - x0f;
        int y0 = (int)y0f, x0 = (int)x0f;
        int y1 = y0 + 1,   x1 = x0 + 1;
        bool vy0 = (y0 >= 0) & (y0 < H_);
        bool vy1 = (y1 >= 0) & (y1 < H_);
        bool vx0 = (x0 >= 0) & (x0 < W_);
        bool vx1 = (x1 >= 0) & (x1 < W_);
        float w00 = (1.f - ly) * (1.f - lx) * m * ((vy0 & vx0) ? 1.f : 0.f);
        float w01 = (1.f - ly) * lx         * m * ((vy0 & vx1) ? 1.f : 0.f);
        float w10 = ly * (1.f - lx)         * m * ((vy1 & vx0) ? 1.f : 0.f);
        float w11 = ly * lx                 * m * ((vy1 & vx1) ? 1.f : 0.f);
        unsigned int cy0 = (unsigned)min(max(y0, 0), H_ - 1);
        unsigned int cy1 = (unsigned)min(max(y1, 0), H_ - 1);
        unsigned int cx0 = (unsigned)min(max(x0, 0), W_ - 1);
        unsigned int cx1 = (unsigned)min(max(x1, 0), W_ - 1);
        sIdx[e] = make_uint2((cy0 * W_ + cx0) | ((cy0 * W_ + cx1) << 16),
                             (cy1 * W_ + cx0) | ((cy1 * W_ + cx1) << 16));
        sW[e]   = make_float4(w00, w01, w10, w11);
    }

    const float* xn = x + (size_t)n * C_ * P_;
    const int pl   = tid >> 2;
    const int pl9  = pl * K_;
    const int ckb  = (tid & 3) * 8;
    const int wco  = tid >> 1;
    const int wck  = (tid & 1) * 16;

    const int lane = tid & 63;
    const int wid  = tid >> 6;
    const int wm   = (wid & 1) * 128;
    const int wp   = (wid >> 1) * 32;
    const int l15  = lane & 15;
    const int l4   = lane >> 4;

    f32x4 acc[8][2] = {};

    for (int ck0 = 0; ck0 < CK_; ck0 += 32) {
        __syncthreads();
        {
            const float4* wsrc = (const float4*)(weight + (size_t)wco * CK_ + ck0 + wck);
            float4 wa = wsrc[0], wb = wsrc[1], wc = wsrc[2], wd = wsrc[3];
            uint4 q0, q1;
            q0.x = f2bf(wa.x) | ((unsigned)f2bf(wa.y) << 16);
            q0.y = f2bf(wa.z) | ((unsigned)f2bf(wa.w) << 16);
            q0.z = f2bf(wb.x) | ((unsigned)f2bf(wb.y) << 16);
            q0.w = f2bf(wb.z) | ((unsigned)f2bf(wb.w) << 16);
            q1.x = f2bf(wc.x) | ((unsigned)f2bf(wc.y) << 16);
            q1.y = f2bf(wc.z) | ((unsigned)f2bf(wc.w) << 16);
            q1.z = f2bf(wd.x) | ((unsigned)f2bf(wd.y) << 16);
            q1.w = f2bf(wd.z) | ((unsigned)f2bf(wd.w) << 16);
            *(uint4*)&sWs[wco * 32 + wck]     = q0;
            *(uint4*)&sWs[wco * 32 + wck + 8] = q1;
        }
        {
            int ckstart = ck0 + ckb;
            int cc = ckstart / 9;
            int kk = ckstart - cc * 9;
            unsigned int packed[4];
            unsigned short colv[8];
            #pragma unroll
            for (int j = 0; j < 8; ++j) {
                int e = pl9 + kk;
                uint2  id = sIdx[e];
                float4 wv = sW[e];
                const float* xp = xn + ((size_t)cc << 12);
                float v = wv.x * xp[id.x & 0xFFFFu]
                        + wv.y * xp[id.x >> 16]
                        + wv.z * xp[id.y & 0xFFFFu]
                        + wv.w * xp[id.y >> 16];
                colv[j] = f2bf(v);
                ++kk; if (kk == 9) { kk = 0; ++cc; }
            }
            packed[0] = colv[0] | ((unsigned)colv[1] << 16);
            packed[1] = colv[2] | ((unsigned)colv[3] << 16);
            packed[2] = colv[4] | ((unsigned)colv[5] << 16);
            packed[3] = colv[6] | ((unsigned)colv[7] << 16);
            *(uint4*)&sBs[pl * 32 + ckb] = *(uint4*)packed;
        }
        __syncthreads();
        bf16x8 bfr0 = *(const bf16x8*)&sBs[(wp + l15)      * 32 + l4 * 8];
        bf16x8 bfr1 = *(const bf16x8*)&sBs[(wp + 16 + l15) * 32 + l4 * 8];
        #pragma unroll
        for (int m = 0; m < 8; ++m) {
            bf16x8 afr = *(const bf16x8*)&sWs[(wm + m * 16 + l15) * 32 + l4 * 8];
            acc[m][0] = __builtin_amdgcn_mfma_f32_16x16x32_bf16(afr, bfr0, acc[m][0], 0, 0, 0);
            acc[m][1] = __builtin_amdgcn_mfma_f32_16x16x32_bf16(afr, bfr1, acc[m][1], 0, 0, 0);
        }
    }

    float* outn = out + (size_t)n * CO_ * P_;
    #pragma unroll
    for (int m = 0; m < 8; ++m) {
        int co = wm + m * 16 + l4 * 4;
        #pragma unroll
        for (int nn = 0; nn < 2; ++nn) {
            int p = p0 + wp + nn * 16 + l15;
            #pragma unroll
            for (int r = 0; r < 4; ++r) {
                outn[(size_t)(co + r) * P_ + p] = acc[m][nn][r];
            }
        }
    }
}

extern "C" void kernel_launch(void* const* d_in, const int* in_sizes, int n_in,
                              void* d_out, int out_size, void* d_ws, size_t ws_size,
                              hipStream_t stream) {
    const float* x      = (const float*)d_in[0];
    const float* offset = (const float*)d_in[1];
    const float* mask   = (const float*)d_in[2];
    const float* weight = (const float*)d_in[3];
    float* out = (float*)d_out;

    const size_t xT_elems = (size_t)N_ * P_ * C_;            // 8,388,608 ushort
    const size_t Wt_elems = (size_t)CO_ * CK_;               //   589,824 ushort
    const size_t need     = (xT_elems + Wt_elems) * sizeof(unsigned short); // 17,956,864 B

    if (ws_size >= need) {
        unsigned short* xT = (unsigned short*)d_ws;
        unsigned short* Wt = xT + xT_elems;
        transpose_x<<<dim3(P_ / 64, C_ / 64, N_), dim3(256), 0, stream>>>(x, xT);
        reorder_w<<<dim3(CO_), dim3(256), 0, stream>>>(weight, Wt);
        // grid: 8 n (XCD-pin) x 32 p-tiles = 256 blocks = 1 block/CU, 16 waves
        dcn_main<<<dim3((P_ / BN) * N_), dim3(NTHR), 0, stream>>>(xT, Wt, offset, mask, out);
    } else if (ws_size >= (8u << 20)) {
        dcn_fb<1><<<dim3(P_ / 128, N_), dim3(512), 0, stream>>>(x, offset, mask, weight, out);
    } else {
        dcn_fb<0><<<dim3(P_ / 128, N_), dim3(512), 0, stream>>>(x, offset, mask, weight, out);
    }
}

// Round 17
// 71.398 us; speedup vs baseline: 1.5133x; 1.0008x over previous
//
#include <hip/hip_runtime.h>
#include <hip/hip_bf16.h>
#include <hip/hip_fp16.h>
#include <stdint.h>

#define N_   8
#define C_   256
#define H_   64
#define W_   64
#define CO_  256
#define K_   9
#define HO_  64
#define WO_  64
#define CK_  (C_ * K_)    // 2304
#define P_   (HO_ * WO_)  // 4096

#define BN   128          // p per block
#define BK   64           // ck per K-step (2 MFMA K-slices)
#define NT   36           // K-steps: 9 taps x 4 channel-quarters
#define NTHR 1024         // 16 waves = 4 waves/SIMD

typedef __attribute__((ext_vector_type(8))) _Float16 f16x8;
typedef __attribute__((ext_vector_type(4))) float f32x4;

__device__ __forceinline__ unsigned short f2bf(float f) {
    uint32_t u = __builtin_bit_cast(uint32_t, f);
    uint32_t r = (u + 0x7FFFu + ((u >> 16) & 1u)) >> 16;
    return (unsigned short)r;
}
__device__ __forceinline__ float bf2f(unsigned short u) {
    return __builtin_bit_cast(float, (uint32_t)u << 16);
}
__device__ __forceinline__ unsigned short f2h(float f) {
    return __builtin_bit_cast(unsigned short, (_Float16)f);
}

// ================= FAST PATH (needs 17,956,864 B of d_ws) =================

// pre-pass A: x[n][c][hw] f32 -> xT[n][hw][c] f16
__global__ __launch_bounds__(256)
void transpose_x(const float* __restrict__ x, unsigned short* __restrict__ xT) {
    __shared__ float t[64][65];
    const int n  = blockIdx.z;
    const int c0 = blockIdx.y * 64;
    const int h0 = blockIdx.x * 64;
    const int tx = threadIdx.x & 63;
    const int ty = threadIdx.x >> 6;   // 0..3
    const float* xp = x + ((size_t)n * C_ + c0) * P_ + h0;
    #pragma unroll
    for (int i = 0; i < 16; ++i) {
        int c = ty * 16 + i;
        t[c][tx] = xp[(size_t)c * P_ + tx];
    }
    __syncthreads();
    unsigned short* op = xT + ((size_t)n * P_ + h0) * C_ + c0;
    #pragma unroll
    for (int i = 0; i < 16; ++i) {
        int hw = ty * 16 + i;
        op[(size_t)hw * C_ + tx] = f2h(t[tx][hw]);
    }
}

// pre-pass B: weight[co][c][k] f32 -> Wt[co][k][c] f16
__global__ __launch_bounds__(256)
void reorder_w(const float* __restrict__ w, unsigned short* __restrict__ Wt) {
    const int co = blockIdx.x;
    const int c  = threadIdx.x;
    const float* src = w + (size_t)co * CK_ + (size_t)c * K_;
    float v[9];
    #pragma unroll
    for (int k = 0; k < 9; ++k) v[k] = src[k];
    #pragma unroll
    for (int k = 0; k < 9; ++k)
        Wt[(size_t)co * CK_ + k * C_ + c] = f2h(v[k]);
}

// Raw-barrier helper: keeps in-flight vmem loads alive across the barrier
// (__syncthreads would force s_waitcnt vmcnt(0) first).
__device__ __forceinline__ void barrier_lgkm_only() {
    __builtin_amdgcn_sched_barrier(0);
    asm volatile("s_waitcnt lgkmcnt(0)" ::: "memory");
    __builtin_amdgcn_s_barrier();
    __builtin_amdgcn_sched_barrier(0);
}

// packed bilinear combine of one u32 (2 f16 channels) per corner
#define COMB(dst, A, B, Cc, D) do {                                   \
    __half2 _v = __hmul2(W0, __builtin_bit_cast(__half2, (A)));       \
    _v = __hfma2(W1, __builtin_bit_cast(__half2, (B)), _v);           \
    _v = __hfma2(W2, __builtin_bit_cast(__half2, (Cc)), _v);          \
    _v = __hfma2(W3, __builtin_bit_cast(__half2, (D)), _v);           \
    (dst) = __builtin_bit_cast(unsigned, _v); } while (0)

// Round 17: r14 base (best: 57.1us) with ONE change — weight staging uses
// r13's conflict-free pattern. r14's 4-threads/row role made the per-16-lane
// slot index a 2bit^2bit XOR -> only 4 distinct slots -> 4-way bank conflict
// on every weight store (2.36M/dispatch). r13's 2-threads/row role (8 rows
// per quarter-wave, slot=(4h+i)^(r&7) spans all 8 slots, 2-way=free)
// measured 0 conflicts. Weights now staged by waves 0-7 only (512 threads,
// 64B each); waves 8-15 sample only. Wave-uniform branch. Everything else
// identical to r14 (1-barrier double-buffer, counted prefetch, XOR swizzle,
// f16 packed path, 16 waves, XCD-pin, launch_bounds(1024,4)).
__global__ __launch_bounds__(NTHR, 4)
void dcn_main(const unsigned short* __restrict__ xT,
              const unsigned short* __restrict__ Wt,
              const float* __restrict__ offset,
              const float* __restrict__ mask,
              float* __restrict__ out) {
    __shared__ uint2 sIdx[BN * K_];               //  9216 B (write-once)
    __shared__ uint4 sWd [BN * K_];               // 18432 B (write-once)
    __shared__ unsigned short sWs[2][CO_ * BK];   // 64 KB double-buffered
    __shared__ unsigned short sBs[2][BN * BK];    // 32 KB double-buffered -> 125952 B

    const int tid = threadIdx.x;
    // XCD-pin: bid%8 = XCD = batch image; per-XCD set ~3.2MB fits 4MB L2.
    const int bid = blockIdx.x;
    const int n   = bid & 7;
    const int p0  = (bid >> 3) * BN;   // 32 p-tiles per image

    for (int e = tid; e < BN * K_; e += NTHR) {
        int pl = e / K_;
        int k  = e - pl * K_;
        int p  = p0 + pl;
        int ho = p >> 6, wo = p & 63;
        float offy = offset[(size_t)((n * 2 * K_ + 2 * k)     * P_) + p];
        float offx = offset[(size_t)((n * 2 * K_ + 2 * k + 1) * P_) + p];
        float m    = mask  [(size_t)((n * K_ + k) * P_) + p];
        float py = (float)(k / 3 + ho - 1) + offy;
        float px = (float)(k % 3 + wo - 1) + offx;
        float y0f = floorf(py), x0f = floorf(px);
        float ly = py - y0f,   lx = px - x0f;
        int y0 = (int)y0f, x0 = (int)x0f;
        int y1 = y0 + 1,   x1 = x0 + 1;
        bool vy0 = (y0 >= 0) & (y0 < H_);
        bool vy1 = (y1 >= 0) & (y1 < H_);
        bool vx0 = (x0 >= 0) & (x0 < W_);
        bool vx1 = (x1 >= 0) & (x1 < W_);
        float w00 = (1.f - ly) * (1.f - lx) * m * ((vy0 & vx0) ? 1.f : 0.f);
        float w01 = (1.f - ly) * lx         * m * ((vy0 & vx1) ? 1.f : 0.f);
        float w10 = ly * (1.f - lx)         * m * ((vy1 & vx0) ? 1.f : 0.f);
        float w11 = ly * lx                 * m * ((vy1 & vx1) ? 1.f : 0.f);
        unsigned int cy0 = (unsigned)min(max(y0, 0), H_ - 1);
        unsigned int cy1 = (unsigned)min(max(y1, 0), H_ - 1);
        unsigned int cx0 = (unsigned)min(max(x0, 0), W_ - 1);
        unsigned int cx1 = (unsigned)min(max(x1, 0), W_ - 1);
        sIdx[e] = make_uint2((cy0 * W_ + cx0) | ((cy0 * W_ + cx1) << 16),
                             (cy1 * W_ + cx0) | ((cy1 * W_ + cx1) << 16));
        sWd[e] = make_uint4((unsigned)f2h(w00) * 0x10001u,
                            (unsigned)f2h(w01) * 0x10001u,
                            (unsigned)f2h(w10) * 0x10001u,
                            (unsigned)f2h(w11) * 0x10001u);
    }
    __syncthreads();   // params visible before prefetch(0) reads sIdx

    const unsigned short* xTn = xT + (size_t)n * P_ * C_;

    // ---- roles ----
    // sampling (all 1024 threads): 8 threads per p-row, 8 channels (16B) each
    const int spl = tid >> 3;                 // 0..127
    const int cs  = tid & 7;                  // channel slot (8 f16 = 16B)
    const int boff = spl * 128 + ((cs ^ (spl & 7)) << 4);
    // weight staging (waves 0-7 only): 2 threads per co row, 4x 16B slots
    const int wid  = tid >> 6;                // 0..15
    const bool wstage = (wid < 8);
    const int wco  = (tid & 511) >> 1;        // 0..255
    const int wchq = (tid & 1) * 4;           // slot base 0 or 4
    const int wswz = wco & 7;
    const int woff = wco * 128;
    const unsigned short* wsrcbase = Wt + (size_t)wco * CK_ + (tid & 1) * 32;

    const int lane = tid & 63;
    const int wm   = (wid & 7) * 32;          // 8 co-groups
    const int wp   = (wid >> 3) * 64;         // 2 p-groups
    const int l15  = lane & 15;
    const int l4   = lane >> 4;
    const int slA  = l4 ^ (l15 & 7);          // ks=0 slot; ks=1 -> ^4

    f32x4 acc[2][4] = {};

    // prefetch registers (one tile ahead, in flight across the barrier)
    uint4 qa, qb, qc, qd;          // 4 corners x 8 f16 (all threads)
    uint4 wq0, wq1, wq2, wq3;      // 64B of weight row (waves 0-7 only)

#define PREF(TT) {                                                        \
        const int kn  = (TT) >> 2;                                        \
        const int c0n = ((TT) & 3) * 64;                                  \
        if (wstage) {                                                     \
            const unsigned short* ws = wsrcbase + kn * C_ + c0n;          \
            wq0 = *(const uint4*)(ws);                                    \
            wq1 = *(const uint4*)(ws + 8);                                \
            wq2 = *(const uint4*)(ws + 16);                               \
            wq3 = *(const uint4*)(ws + 24);                               \
        }                                                                 \
        uint2 id = sIdx[spl * K_ + kn];                                   \
        const unsigned short* base = xTn + c0n + cs * 8;                  \
        qa = *(const uint4*)(base + ((size_t)(id.x & 0xFFFFu) << 8));     \
        qb = *(const uint4*)(base + ((size_t)(id.x >> 16)     << 8));     \
        qc = *(const uint4*)(base + ((size_t)(id.y & 0xFFFFu) << 8));     \
        qd = *(const uint4*)(base + ((size_t)(id.y >> 16)     << 8));     \
    }

#define STAGE(TT, WB, BB) {                                               \
        if (wstage) {                                                     \
            char* wrB = (char*)(WB) + woff;                               \
            *(uint4*)(wrB + (((wchq + 0) ^ wswz) << 4)) = wq0;            \
            *(uint4*)(wrB + (((wchq + 1) ^ wswz) << 4)) = wq1;            \
            *(uint4*)(wrB + (((wchq + 2) ^ wswz) << 4)) = wq2;            \
            *(uint4*)(wrB + (((wchq + 3) ^ wswz) << 4)) = wq3;            \
        }                                                                 \
        uint4 wv = sWd[spl * K_ + ((TT) >> 2)];                           \
        __half2 W0 = __builtin_bit_cast(__half2, wv.x);                   \
        __half2 W1 = __builtin_bit_cast(__half2, wv.y);                   \
        __half2 W2 = __builtin_bit_cast(__half2, wv.z);                   \
        __half2 W3 = __builtin_bit_cast(__half2, wv.w);                   \
        uint4 r;                                                          \
        COMB(r.x, qa.x, qb.x, qc.x, qd.x);                                \
        COMB(r.y, qa.y, qb.y, qc.y, qd.y);                                \
        COMB(r.z, qa.z, qb.z, qc.z, qd.z);                                \
        COMB(r.w, qa.w, qb.w, qc.w, qd.w);                                \
        *(uint4*)((char*)(BB) + boff) = r;                                \
    }

    // ---- prologue: tile 0 -> regs -> buf0; tile 1 -> regs ----
    PREF(0)
    STAGE(0, sWs[0], sBs[0])
    PREF(1)

    for (int t = 0; t < NT; ++t) {
        const int br = t & 1;
        const char* wR = (const char*)sWs[br];
        const char* bR = (const char*)sBs[br];

        // single barrier: buf[br] writes (last iter) visible; buf[br^1] reads
        // (last iter's MFMA) complete. In-flight global loads survive.
        barrier_lgkm_only();

        // ks=0 fragment reads (in regs across the stage)
        f16x8 A0, A1, B0, B1, B2, B3;
        {
            const int sl = slA;
            B0 = *(const f16x8*)(bR + (wp      + l15) * 128 + (sl << 4));
            B1 = *(const f16x8*)(bR + (wp + 16 + l15) * 128 + (sl << 4));
            B2 = *(const f16x8*)(bR + (wp + 32 + l15) * 128 + (sl << 4));
            B3 = *(const f16x8*)(bR + (wp + 48 + l15) * 128 + (sl << 4));
            A0 = *(const f16x8*)(wR + (wm      + l15) * 128 + (sl << 4));
            A1 = *(const f16x8*)(wR + (wm + 16 + l15) * 128 + (sl << 4));
        }

        // stage tile t+1 into the write buffer (different buffer -> no
        // second barrier); then issue tile t+2's global loads
        if (t + 1 < NT) {
            if (br) { STAGE(t + 1, sWs[0], sBs[0]) }
            else    { STAGE(t + 1, sWs[1], sBs[1]) }
            if (t + 2 < NT) PREF(t + 2)
        }

        // MFMA ks=0 (co-schedules with the ds_writes above)
        acc[0][0] = __builtin_amdgcn_mfma_f32_16x16x32_f16(A0, B0, acc[0][0], 0, 0, 0);
        acc[0][1] = __builtin_amdgcn_mfma_f32_16x16x32_f16(A0, B1, acc[0][1], 0, 0, 0);
        acc[0][2] = __builtin_amdgcn_mfma_f32_16x16x32_f16(A0, B2, acc[0][2], 0, 0, 0);
        acc[0][3] = __builtin_amdgcn_mfma_f32_16x16x32_f16(A0, B3, acc[0][3], 0, 0, 0);
        acc[1][0] = __builtin_amdgcn_mfma_f32_16x16x32_f16(A1, B0, acc[1][0], 0, 0, 0);
        acc[1][1] = __builtin_amdgcn_mfma_f32_16x16x32_f16(A1, B1, acc[1][1], 0, 0, 0);
        acc[1][2] = __builtin_amdgcn_mfma_f32_16x16x32_f16(A1, B2, acc[1][2], 0, 0, 0);
        acc[1][3] = __builtin_amdgcn_mfma_f32_16x16x32_f16(A1, B3, acc[1][3], 0, 0, 0);

        // ks=1 fragment reads + MFMA
        {
            const int sl = slA ^ 4;
            B0 = *(const f16x8*)(bR + (wp      + l15) * 128 + (sl << 4));
            B1 = *(const f16x8*)(bR + (wp + 16 + l15) * 128 + (sl << 4));
            B2 = *(const f16x8*)(bR + (wp + 32 + l15) * 128 + (sl << 4));
            B3 = *(const f16x8*)(bR + (wp + 48 + l15) * 128 + (sl << 4));
            A0 = *(const f16x8*)(wR + (wm      + l15) * 128 + (sl << 4));
            A1 = *(const f16x8*)(wR + (wm + 16 + l15) * 128 + (sl << 4));
        }
        acc[0][0] = __builtin_amdgcn_mfma_f32_16x16x32_f16(A0, B0, acc[0][0], 0, 0, 0);
        acc[0][1] = __builtin_amdgcn_mfma_f32_16x16x32_f16(A0, B1, acc[0][1], 0, 0, 0);
        acc[0][2] = __builtin_amdgcn_mfma_f32_16x16x32_f16(A0, B2, acc[0][2], 0, 0, 0);
        acc[0][3] = __builtin_amdgcn_mfma_f32_16x16x32_f16(A0, B3, acc[0][3], 0, 0, 0);
        acc[1][0] = __builtin_amdgcn_mfma_f32_16x16x32_f16(A1, B0, acc[1][0], 0, 0, 0);
        acc[1][1] = __builtin_amdgcn_mfma_f32_16x16x32_f16(A1, B1, acc[1][1], 0, 0, 0);
        acc[1][2] = __builtin_amdgcn_mfma_f32_16x16x32_f16(A1, B2, acc[1][2], 0, 0, 0);
        acc[1][3] = __builtin_amdgcn_mfma_f32_16x16x32_f16(A1, B3, acc[1][3], 0, 0, 0);
    }
#undef PREF
#undef STAGE

    float* outn = out + (size_t)n * CO_ * P_;
    #pragma unroll
    for (int m = 0; m < 2; ++m) {
        int co = wm + m * 16 + l4 * 4;
        #pragma unroll
        for (int nn = 0; nn < 4; ++nn) {
            int p = p0 + wp + nn * 16 + l15;
            #pragma unroll
            for (int r = 0; r < 4; ++r) {
                outn[(size_t)(co + r) * P_ + p] = acc[m][nn][r];
            }
        }
    }
}

// ================= FALLBACK (round-2 kernel, zero scratch, proven pass) =================
template <int TAG>
__global__ __launch_bounds__(512, 2)
void dcn_fb(const float* __restrict__ x,
            const float* __restrict__ offset,
            const float* __restrict__ mask,
            const float* __restrict__ weight,
            float* __restrict__ out) {
    typedef __attribute__((ext_vector_type(8))) short bf16x8;
    __shared__ uint2  sIdx[128 * K_];
    __shared__ float4 sW  [128 * K_];
    __shared__ unsigned short sWs[CO_ * 32];
    __shared__ unsigned short sBs[128 * 32];

    const int tid = threadIdx.x;
    const int n  = blockIdx.y;
    const int p0 = blockIdx.x * 128;

    for (int e = tid; e < 128 * K_; e += 512) {
        int pl = e / K_;
        int k  = e - pl * K_;
        int p  = p0 + pl;
        int ho = p >> 6, wo = p & 63;
        float offy = offset[(size_t)((n * 2 * K_ + 2 * k)     * P_) + p];
        float offx = offset[(size_t)((n * 2 * K_ + 2 * k + 1) * P_) + p];
        float m    = mask  [(size_t)((n * K_ + k) * P_) + p];
        float py = (float)(k / 3 + ho - 1) + offy;
        float px = (float)(k % 3 + wo - 1) + offx;
        float y0f = floorf(py), x0f = floorf(px);
        float ly = py - y0f,   lx = px - x0f;
        int y0 = (int)y0f, x0 = (int)x0f;
        int y1 = y0 + 1,   x1 = x0 + 1;
        bool vy0 = (y0 >= 0) & (y0 < H_);
        bool vy1 = (y1 >= 0) & (y1 < H_);
        bool vx0 = (x0 >= 0) & (x0 < W_);
        bool vx1 = (x1 >= 0) & (x1 < W_);
        float w00 = (1.f - ly) * (1.f - lx) * m * ((vy0 & vx0) ? 1.f : 0.f);
        float w01 = (1.f - ly) * lx         * m * ((vy0 & vx1) ? 1.f : 0.f);
        float w10 = ly * (1.f - lx)         * m * ((vy1 & vx0) ? 1.f : 0.f);
        float w11 = ly * lx                 * m * ((vy1 & vx1) ? 1.f : 0.f);
        unsigned int cy0 = (unsigned)min(max(y0, 0), H_ - 1);
        unsigned int cy1 = (unsigned)min(max(y1, 0), H_ - 1);
        unsigned int cx0 = (unsigned)min(max(x0, 0), W_ - 1);
        unsigned int cx1 = (unsigned)min(max(x1, 0), W_ - 1);
        sIdx[e] = make_uint2((cy0 * W_ + cx0) | ((cy0 * W_ + cx1) << 16),
                             (cy1 * W_ + cx0) | ((cy1 * W_ + cx1) << 16));
        sW[e]   = make_float4(w00, w01, w10, w11);
    }

    const float* xn = x + (size_t)n * C_ * P_;
    const int pl   = tid >> 2;
    const int pl9  = pl * K_;
    const int ckb  = (tid & 3) * 8;
    const int wco  = tid >> 1;
    const int wck  = (tid & 1) * 16;

    const int lane = tid & 63;
    const int wid  = tid >> 6;
    const int wm   = (wid & 1) * 128;
    const int wp   = (wid >> 1) * 32;
    const int l15  = lane & 15;
    const int l4   = lane >> 4;

    f32x4 acc[8][2] = {};

    for (int ck0 = 0; ck0 < CK_; ck0 += 32) {
        __syncthreads();
        {
            const float4* wsrc = (const float4*)(weight + (size_t)wco * CK_ + ck0 + wck);
            float4 wa = wsrc[0], wb = wsrc[1], wc = wsrc[2], wd = wsrc[3];
            uint4 q0, q1;
            q0.x = f2bf(wa.x) | ((unsigned)f2bf(wa.y) << 16);
            q0.y = f2bf(wa.z) | ((unsigned)f2bf(wa.w) << 16);
            q0.z = f2bf(wb.x) | ((unsigned)f2bf(wb.y) << 16);
            q0.w = f2bf(wb.z) | ((unsigned)f2bf(wb.w) << 16);
            q1.x = f2bf(wc.x) | ((unsigned)f2bf(wc.y) << 16);
            q1.y = f2bf(wc.z) | ((unsigned)f2bf(wc.w) << 16);
            q1.z = f2bf(wd.x) | ((unsigned)f2bf(wd.y) << 16);
            q1.w = f2bf(wd.z) | ((unsigned)f2bf(wd.w) << 16);
            *(uint4*)&sWs[wco * 32 + wck]     = q0;
            *(uint4*)&sWs[wco * 32 + wck + 8] = q1;
        }
        {
            int ckstart = ck0 + ckb;
            int cc = ckstart / 9;
            int kk = ckstart - cc * 9;
            unsigned int packed[4];
            unsigned short colv[8];
            #pragma unroll
            for (int j = 0; j < 8; ++j) {
                int e = pl9 + kk;
                uint2  id = sIdx[e];
                float4 wv = sW[e];
                const float* xp = xn + ((size_t)cc << 12);
                float v = wv.x * xp[id.x & 0xFFFFu]
                        + wv.y * xp[id.x >> 16]
                        + wv.z * xp[id.y & 0xFFFFu]
                        + wv.w * xp[id.y >> 16];
                colv[j] = f2bf(v);
                ++kk; if (kk == 9) { kk = 0; ++cc; }
            }
            packed[0] = colv[0] | ((unsigned)colv[1] << 16);
            packed[1] = colv[2] | ((unsigned)colv[3] << 16);
            packed[2] = colv[4] | ((unsigned)colv[5] << 16);
            packed[3] = colv[6] | ((unsigned)colv[7] << 16);
            *(uint4*)&sBs[pl * 32 + ckb] = *(uint4*)packed;
        }
        __syncthreads();
        bf16x8 bfr0 = *(const bf16x8*)&sBs[(wp + l15)      * 32 + l4 * 8];
        bf16x8 bfr1 = *(const bf16x8*)&sBs[(wp + 16 + l15) * 32 + l4 * 8];
        #pragma unroll
        for (int m = 0; m < 8; ++m) {
            bf16x8 afr = *(const bf16x8*)&sWs[(wm + m * 16 + l15) * 32 + l4 * 8];
            acc[m][0] = __builtin_amdgcn_mfma_f32_16x16x32_bf16(afr, bfr0, acc[m][0], 0, 0, 0);
            acc[m][1] = __builtin_amdgcn_mfma_f32_16x16x32_bf16(afr, bfr1, acc[m][1], 0, 0, 0);
        }
    }

    float* outn = out + (size_t)n * CO_ * P_;
    #pragma unroll
    for (int m = 0; m < 8; ++m) {
        int co = wm + m * 16 + l4 * 4;
        #pragma unroll
        for (int nn = 0; nn < 2; ++nn) {
            int p = p0 + wp + nn * 16 + l15;
            #pragma unroll
            for (int r = 0; r < 4; ++r) {
                outn[(size_t)(co + r) * P_ + p] = acc[m][nn][r];
            }
        }
    }
}

extern "C" void kernel_launch(void* const* d_in, const int* in_sizes, int n_in,
                              void* d_out, int out_size, void* d_ws, size_t ws_size,
                              hipStream_t stream) {
    const float* x      = (const float*)d_in[0];
    const float* offset = (const float*)d_in[1];
    const float* mask   = (const float*)d_in[2];
    const float* weight = (const float*)d_in[3];
    float* out = (float*)d_out;

    const size_t xT_elems = (size_t)N_ * P_ * C_;            // 8,388,608 ushort
    const size_t Wt_elems = (size_t)CO_ * CK_;               //   589,824 ushort
    const size_t need     = (xT_elems + Wt_elems) * sizeof(unsigned short); // 17,956,864 B

    if (ws_size >= need) {
        unsigned short* xT = (unsigned short*)d_ws;
        unsigned short* Wt = xT + xT_elems;
        transpose_x<<<dim3(P_ / 64, C_ / 64, N_), dim3(256), 0, stream>>>(x, xT);
        reorder_w<<<dim3(CO_), dim3(256), 0, stream>>>(weight, Wt);
        // grid: 8 n (XCD-pin) x 32 p-tiles = 256 blocks = 1 block/CU, 16 waves
        dcn_main<<<dim3((P_ / BN) * N_), dim3(NTHR), 0, stream>>>(xT, Wt, offset, mask, out);
    } else if (ws_size >= (8u << 20)) {
        dcn_fb<1><<<dim3(P_ / 128, N_), dim3(512), 0, stream>>>(x, offset, mask, weight, out);
    } else {
        dcn_fb<0><<<dim3(P_ / 128, N_), dim3(512), 0, stream>>>(x, offset, mask, weight, out);
    }
}

// Round 20
// 69.935 us; speedup vs baseline: 1.5450x; 1.0209x over previous
//
#include <hip/hip_runtime.h>
#include <hip/hip_bf16.h>
#include <hip/hip_fp16.h>
#include <stdint.h>

#define N_   8
#define C_   256
#define H_   64
#define W_   64
#define CO_  256
#define K_   9
#define HO_  64
#define WO_  64
#define CK_  (C_ * K_)    // 2304
#define P_   (HO_ * WO_)  // 4096

#define BN   128          // p per block
#define BK   64           // ck per K-step (2 MFMA K-slices)
#define NT   36           // K-steps: 9 taps x 4 channel-quarters
#define NTHR 1024         // 16 waves = 4 waves/SIMD
#define TBLK 2048         // transpose blocks in fused pre-pass

typedef __attribute__((ext_vector_type(8))) _Float16 f16x8;
typedef __attribute__((ext_vector_type(4))) float f32x4;

__device__ __forceinline__ unsigned short f2bf(float f) {
    uint32_t u = __builtin_bit_cast(uint32_t, f);
    uint32_t r = (u + 0x7FFFu + ((u >> 16) & 1u)) >> 16;
    return (unsigned short)r;
}
__device__ __forceinline__ float bf2f(unsigned short u) {
    return __builtin_bit_cast(float, (uint32_t)u << 16);
}
__device__ __forceinline__ unsigned short f2h(float f) {
    return __builtin_bit_cast(unsigned short, (_Float16)f);
}

// ================= FAST PATH (needs 17,956,864 B of d_ws) =================

// Fused pre-pass: blocks [0,TBLK) transpose x[n][c][hw] f32 -> xT[n][hw][c]
// f16 (vectorized 16B stores — old version stored 2B/lane); blocks
// [TBLK, TBLK+CO_) reorder weight -> Wt[co][k][c] f16. One launch instead of
// two: r14 post-mortem showed 11.9us of the 69us total was pre-pass+gaps.
__global__ __launch_bounds__(256)
void prep_fused(const float* __restrict__ x, unsigned short* __restrict__ xT,
                const float* __restrict__ w, unsigned short* __restrict__ Wt) {
    const int bid = blockIdx.x;
    if (bid < TBLK) {
        // transpose tile: 64 c x 64 hw
        const int bx = bid & 63;         // hw tile
        const int by = (bid >> 6) & 3;   // c tile
        const int n  = bid >> 8;         // image
        __shared__ unsigned short t[64][72];   // +8 pad
        const int tx = threadIdx.x & 63;
        const int ty = threadIdx.x >> 6;       // 0..3
        const float* xp = x + ((size_t)n * C_ + by * 64) * P_ + bx * 64;
        #pragma unroll
        for (int i = 0; i < 16; ++i) {
            int c = ty * 16 + i;
            t[c][tx] = f2h(xp[(size_t)c * P_ + tx]);
        }
        __syncthreads();
        // write: 4 threads per hw row, 16 channels (32B) each
        const int row = threadIdx.x >> 2;
        const int c0  = (threadIdx.x & 3) * 16;
        unsigned short vals[16];
        #pragma unroll
        for (int j = 0; j < 16; ++j) vals[j] = t[c0 + j][row];
        unsigned short* op = xT + ((size_t)n * P_ + bx * 64 + row) * C_ + by * 64 + c0;
        *(uint4*)op       = *(uint4*)&vals[0];
        *(uint4*)(op + 8) = *(uint4*)&vals[8];
    } else {
        const int co = bid - TBLK;
        const int c  = threadIdx.x;
        const float* src = w + (size_t)co * CK_ + (size_t)c * K_;
        float v[9];
        #pragma unroll
        for (int k = 0; k < 9; ++k) v[k] = src[k];
        #pragma unroll
        for (int k = 0; k < 9; ++k)
            Wt[(size_t)co * CK_ + k * C_ + c] = f2h(v[k]);
    }
}

// Raw-barrier helper: keeps in-flight vmem loads alive across the barrier
// (__syncthreads would force s_waitcnt vmcnt(0) first).
__device__ __forceinline__ void barrier_lgkm_only() {
    __builtin_amdgcn_sched_barrier(0);
    asm volatile("s_waitcnt lgkmcnt(0)" ::: "memory");
    __builtin_amdgcn_s_barrier();
    __builtin_amdgcn_sched_barrier(0);
}

// packed bilinear combine of one u32 (2 f16 channels) per corner
#define COMB(dst, A, B, Cc, D) do {                                   \
    __half2 _v = __hmul2(W0, __builtin_bit_cast(__half2, (A)));       \
    _v = __hfma2(W1, __builtin_bit_cast(__half2, (B)), _v);           \
    _v = __hfma2(W2, __builtin_bit_cast(__half2, (Cc)), _v);          \
    _v = __hfma2(W3, __builtin_bit_cast(__half2, (D)), _v);           \
    (dst) = __builtin_bit_cast(unsigned, _v); } while (0)

// Round 18 dcn_main: r14 byte-identical (best, 57.1us) + T5 s_setprio(1/0)
// around each 8-MFMA cluster. r15/r16/r17 all failed to beat r14's intra-loop
// structure (A-from-L2: uncoalesced; ks-split: epilogue cost; conflict-free
// wstage: conflicts were TLP-absorbed). Waves here have intra-iteration role
// diversity (stage VALU vs MFMA) so setprio has something to arbitrate.
__global__ __launch_bounds__(NTHR, 4)
void dcn_main(const unsigned short* __restrict__ xT,
              const unsigned short* __restrict__ Wt,
              const float* __restrict__ offset,
              const float* __restrict__ mask,
              float* __restrict__ out) {
    __shared__ uint2 sIdx[BN * K_];               //  9216 B (write-once)
    __shared__ uint4 sWd [BN * K_];               // 18432 B (write-once)
    __shared__ unsigned short sWs[2][CO_ * BK];   // 64 KB double-buffered
    __shared__ unsigned short sBs[2][BN * BK];    // 32 KB double-buffered -> 125952 B

    const int tid = threadIdx.x;
    // XCD-pin: bid%8 = XCD = batch image; per-XCD set ~3.2MB fits 4MB L2.
    const int bid = blockIdx.x;
    const int n   = bid & 7;
    const int p0  = (bid >> 3) * BN;   // 32 p-tiles per image

    for (int e = tid; e < BN * K_; e += NTHR) {
        int pl = e / K_;
        int k  = e - pl * K_;
        int p  = p0 + pl;
        int ho = p >> 6, wo = p & 63;
        float offy = offset[(size_t)((n * 2 * K_ + 2 * k)     * P_) + p];
        float offx = offset[(size_t)((n * 2 * K_ + 2 * k + 1) * P_) + p];
        float m    = mask  [(size_t)((n * K_ + k) * P_) + p];
        float py = (float)(k / 3 + ho - 1) + offy;
        float px = (float)(k % 3 + wo - 1) + offx;
        float y0f = floorf(py), x0f = floorf(px);
        float ly = py - y0f,   lx = px - x0f;
        int y0 = (int)y0f, x0 = (int)x0f;
        int y1 = y0 + 1,   x1 = x0 + 1;
        bool vy0 = (y0 >= 0) & (y0 < H_);
        bool vy1 = (y1 >= 0) & (y1 < H_);
        bool vx0 = (x0 >= 0) & (x0 < W_);
        bool vx1 = (x1 >= 0) & (x1 < W_);
        float w00 = (1.f - ly) * (1.f - lx) * m * ((vy0 & vx0) ? 1.f : 0.f);
        float w01 = (1.f - ly) * lx         * m * ((vy0 & vx1) ? 1.f : 0.f);
        float w10 = ly * (1.f - lx)         * m * ((vy1 & vx0) ? 1.f : 0.f);
        float w11 = ly * lx                 * m * ((vy1 & vx1) ? 1.f : 0.f);
        unsigned int cy0 = (unsigned)min(max(y0, 0), H_ - 1);
        unsigned int cy1 = (unsigned)min(max(y1, 0), H_ - 1);
        unsigned int cx0 = (unsigned)min(max(x0, 0), W_ - 1);
        unsigned int cx1 = (unsigned)min(max(x1, 0), W_ - 1);
        sIdx[e] = make_uint2((cy0 * W_ + cx0) | ((cy0 * W_ + cx1) << 16),
                             (cy1 * W_ + cx0) | ((cy1 * W_ + cx1) << 16));
        sWd[e] = make_uint4((unsigned)f2h(w00) * 0x10001u,
                            (unsigned)f2h(w01) * 0x10001u,
                            (unsigned)f2h(w10) * 0x10001u,
                            (unsigned)f2h(w11) * 0x10001u);
    }
    __syncthreads();   // params visible before prefetch(0) reads sIdx

    const unsigned short* xTn = xT + (size_t)n * P_ * C_;

    // ---- roles (identical to r14) ----
    const int spl = tid >> 3;                 // 0..127
    const int cs  = tid & 7;                  // channel slot (8 f16 = 16B)
    const int boff = spl * 128 + ((cs ^ (spl & 7)) << 4);
    const int wco  = tid >> 2;                // 0..255
    const int wsl  = tid & 3;                 // slots wsl and wsl+4
    const int wswz = wco & 7;
    const int woff = wco * 128;
    const unsigned short* wsrcbase = Wt + (size_t)wco * CK_ + wsl * 8;

    const int lane = tid & 63;
    const int wid  = tid >> 6;                // 0..15
    const int wm   = (wid & 7) * 32;          // 8 co-groups
    const int wp   = (wid >> 3) * 64;         // 2 p-groups
    const int l15  = lane & 15;
    const int l4   = lane >> 4;
    const int slA  = l4 ^ (l15 & 7);          // ks=0 slot; ks=1 -> ^4

    f32x4 acc[2][4] = {};

    // prefetch registers (one tile ahead, in flight across the barrier)
    uint4 qa, qb, qc, qd;    // 4 corners x 8 f16
    uint4 wq0, wq1;          // 2x 16B of weight row

#define PREF(TT) {                                                        \
        const int kn  = (TT) >> 2;                                        \
        const int c0n = ((TT) & 3) * 64;                                  \
        const unsigned short* ws = wsrcbase + kn * C_ + c0n;              \
        wq0 = *(const uint4*)(ws);                                        \
        wq1 = *(const uint4*)(ws + 32);                                   \
        uint2 id = sIdx[spl * K_ + kn];                                   \
        const unsigned short* base = xTn + c0n + cs * 8;                  \
        qa = *(const uint4*)(base + ((size_t)(id.x & 0xFFFFu) << 8));     \
        qb = *(const uint4*)(base + ((size_t)(id.x >> 16)     << 8));     \
        qc = *(const uint4*)(base + ((size_t)(id.y & 0xFFFFu) << 8));     \
        qd = *(const uint4*)(base + ((size_t)(id.y >> 16)     << 8));     \
    }

#define STAGE(TT, WB, BB) {                                               \
        char* wrB = (char*)(WB) + woff;                                   \
        *(uint4*)(wrB + ((wsl       ^ wswz) << 4)) = wq0;                 \
        *(uint4*)(wrB + (((wsl + 4) ^ wswz) << 4)) = wq1;                 \
        uint4 wv = sWd[spl * K_ + ((TT) >> 2)];                           \
        __half2 W0 = __builtin_bit_cast(__half2, wv.x);                   \
        __half2 W1 = __builtin_bit_cast(__half2, wv.y);                   \
        __half2 W2 = __builtin_bit_cast(__half2, wv.z);                   \
        __half2 W3 = __builtin_bit_cast(__half2, wv.w);                   \
        uint4 r;                                                          \
        COMB(r.x, qa.x, qb.x, qc.x, qd.x);                                \
        COMB(r.y, qa.y, qb.y, qc.y, qd.y);                                \
        COMB(r.z, qa.z, qb.z, qc.z, qd.z);                                \
        COMB(r.w, qa.w, qb.w, qc.w, qd.w);                                \
        *(uint4*)((char*)(BB) + boff) = r;                                \
    }

    // ---- prologue: tile 0 -> regs -> buf0; tile 1 -> regs ----
    PREF(0)
    STAGE(0, sWs[0], sBs[0])
    PREF(1)

    for (int t = 0; t < NT; ++t) {
        const int br = t & 1;
        const char* wR = (const char*)sWs[br];
        const char* bR = (const char*)sBs[br];

        // single barrier: buf[br] writes (last iter) visible; buf[br^1] reads
        // (last iter's MFMA) complete. In-flight global loads survive.
        barrier_lgkm_only();

        // ks=0 fragment reads (in regs across the stage)
        f16x8 A0, A1, B0, B1, B2, B3;
        {
            const int sl = slA;
            B0 = *(const f16x8*)(bR + (wp      + l15) * 128 + (sl << 4));
            B1 = *(const f16x8*)(bR + (wp + 16 + l15) * 128 + (sl << 4));
            B2 = *(const f16x8*)(bR + (wp + 32 + l15) * 128 + (sl << 4));
            B3 = *(const f16x8*)(bR + (wp + 48 + l15) * 128 + (sl << 4));
            A0 = *(const f16x8*)(wR + (wm      + l15) * 128 + (sl << 4));
            A1 = *(const f16x8*)(wR + (wm + 16 + l15) * 128 + (sl << 4));
        }

        // stage tile t+1 into the write buffer (different buffer -> no
        // second barrier); then issue tile t+2's global loads
        if (t + 1 < NT) {
            if (br) { STAGE(t + 1, sWs[0], sBs[0]) }
            else    { STAGE(t + 1, sWs[1], sBs[1]) }
            if (t + 2 < NT) PREF(t + 2)
        }

        // MFMA ks=0 (co-schedules with the ds_writes above)
        __builtin_amdgcn_s_setprio(1);
        acc[0][0] = __builtin_amdgcn_mfma_f32_16x16x32_f16(A0, B0, acc[0][0], 0, 0, 0);
        acc[0][1] = __builtin_amdgcn_mfma_f32_16x16x32_f16(A0, B1, acc[0][1], 0, 0, 0);
        acc[0][2] = __builtin_amdgcn_mfma_f32_16x16x32_f16(A0, B2, acc[0][2], 0, 0, 0);
        acc[0][3] = __builtin_amdgcn_mfma_f32_16x16x32_f16(A0, B3, acc[0][3], 0, 0, 0);
        acc[1][0] = __builtin_amdgcn_mfma_f32_16x16x32_f16(A1, B0, acc[1][0], 0, 0, 0);
        acc[1][1] = __builtin_amdgcn_mfma_f32_16x16x32_f16(A1, B1, acc[1][1], 0, 0, 0);
        acc[1][2] = __builtin_amdgcn_mfma_f32_16x16x32_f16(A1, B2, acc[1][2], 0, 0, 0);
        acc[1][3] = __builtin_amdgcn_mfma_f32_16x16x32_f16(A1, B3, acc[1][3], 0, 0, 0);
        __builtin_amdgcn_s_setprio(0);

        // ks=1 fragment reads + MFMA
        {
            const int sl = slA ^ 4;
            B0 = *(const f16x8*)(bR + (wp      + l15) * 128 + (sl << 4));
            B1 = *(const f16x8*)(bR + (wp + 16 + l15) * 128 + (sl << 4));
            B2 = *(const f16x8*)(bR + (wp + 32 + l15) * 128 + (sl << 4));
            B3 = *(const f16x8*)(bR + (wp + 48 + l15) * 128 + (sl << 4));
            A0 = *(const f16x8*)(wR + (wm      + l15) * 128 + (sl << 4));
            A1 = *(const f16x8*)(wR + (wm + 16 + l15) * 128 + (sl << 4));
        }
        __builtin_amdgcn_s_setprio(1);
        acc[0][0] = __builtin_amdgcn_mfma_f32_16x16x32_f16(A0, B0, acc[0][0], 0, 0, 0);
        acc[0][1] = __builtin_amdgcn_mfma_f32_16x16x32_f16(A0, B1, acc[0][1], 0, 0, 0);
        acc[0][2] = __builtin_amdgcn_mfma_f32_16x16x32_f16(A0, B2, acc[0][2], 0, 0, 0);
        acc[0][3] = __builtin_amdgcn_mfma_f32_16x16x32_f16(A0, B3, acc[0][3], 0, 0, 0);
        acc[1][0] = __builtin_amdgcn_mfma_f32_16x16x32_f16(A1, B0, acc[1][0], 0, 0, 0);
        acc[1][1] = __builtin_amdgcn_mfma_f32_16x16x32_f16(A1, B1, acc[1][1], 0, 0, 0);
        acc[1][2] = __builtin_amdgcn_mfma_f32_16x16x32_f16(A1, B2, acc[1][2], 0, 0, 0);
        acc[1][3] = __builtin_amdgcn_mfma_f32_16x16x32_f16(A1, B3, acc[1][3], 0, 0, 0);
        __builtin_amdgcn_s_setprio(0);
    }
#undef PREF
#undef STAGE

    float* outn = out + (size_t)n * CO_ * P_;
    #pragma unroll
    for (int m = 0; m < 2; ++m) {
        int co = wm + m * 16 + l4 * 4;
        #pragma unroll
        for (int nn = 0; nn < 4; ++nn) {
            int p = p0 + wp + nn * 16 + l15;
            #pragma unroll
            for (int r = 0; r < 4; ++r) {
                outn[(size_t)(co + r) * P_ + p] = acc[m][nn][r];
            }
        }
    }
}

// ================= FALLBACK (round-2 kernel, zero scratch, proven pass) =================
template <int TAG>
__global__ __launch_bounds__(512, 2)
void dcn_fb(const float* __restrict__ x,
            const float* __restrict__ offset,
            const float* __restrict__ mask,
            const float* __restrict__ weight,
            float* __restrict__ out) {
    typedef __attribute__((ext_vector_type(8))) short bf16x8;
    __shared__ uint2  sIdx[128 * K_];
    __shared__ float4 sW  [128 * K_];
    __shared__ unsigned short sWs[CO_ * 32];
    __shared__ unsigned short sBs[128 * 32];

    const int tid = threadIdx.x;
    const int n  = blockIdx.y;
    const int p0 = blockIdx.x * 128;

    for (int e = tid; e < 128 * K_; e += 512) {
        int pl = e / K_;
        int k  = e - pl * K_;
        int p  = p0 + pl;
        int ho = p >> 6, wo = p & 63;
        float offy = offset[(size_t)((n * 2 * K_ + 2 * k)     * P_) + p];
        float offx = offset[(size_t)((n * 2 * K_ + 2 * k + 1) * P_) + p];
        float m    = mask  [(size_t)((n * K_ + k) * P_) + p];
        float py = (float)(k / 3 + ho - 1) + offy;
        float px = (float)(k % 3 + wo - 1) + offx;
        float y0f = floorf(py), x0f = floorf(px);
        float ly = py - y0f,   lx = px - x0f;
        int y0 = (int)y0f, x0 = (int)x0f;
        int y1 = y0 + 1,   x1 = x0 + 1;
        bool vy0 = (y0 >= 0) & (y0 < H_);
        bool vy1 = (y1 >= 0) & (y1 < H_);
        bool vx0 = (x0 >= 0) & (x0 < W_);
        bool vx1 = (x1 >= 0) & (x1 < W_);
        float w00 = (1.f - ly) * (1.f - lx) * m * ((vy0 & vx0) ? 1.f : 0.f);
        float w01 = (1.f - ly) * lx         * m * ((vy0 & vx1) ? 1.f : 0.f);
        float w10 = ly * (1.f - lx)         * m * ((vy1 & vx0) ? 1.f : 0.f);
        float w11 = ly * lx                 * m * ((vy1 & vx1) ? 1.f : 0.f);
        unsigned int cy0 = (unsigned)min(max(y0, 0), H_ - 1);
        unsigned int cy1 = (unsigned)min(max(y1, 0), H_ - 1);
        unsigned int cx0 = (unsigned)min(max(x0, 0), W_ - 1);
        unsigned int cx1 = (unsigned)min(max(x1, 0), W_ - 1);
        sIdx[e] = make_uint2((cy0 * W_ + cx0) | ((cy0 * W_ + cx1) << 16),
                             (cy1 * W_ + cx0) | ((cy1 * W_ + cx1) << 16));
        sW[e]   = make_float4(w00, w01, w10, w11);
    }

    const float* xn = x + (size_t)n * C_ * P_;
    const int pl   = tid >> 2;
    const int pl9  = pl * K_;
    const int ckb  = (tid & 3) * 8;
    const int wco  = tid >> 1;
    const int wck  = (tid & 1) * 16;

    const int lane = tid & 63;
    const int wid  = tid >> 6;
    const int wm   = (wid & 1) * 128;
    const int wp   = (wid >> 1) * 32;
    const int l15  = lane & 15;
    const int l4   = lane >> 4;

    f32x4 acc[8][2] = {};

    for (int ck0 = 0; ck0 < CK_; ck0 += 32) {
        __syncthreads();
        {
            const float4* wsrc = (const float4*)(weight + (size_t)wco * CK_ + ck0 + wck);
            float4 wa = wsrc[0], wb = wsrc[1], wc = wsrc[2], wd = wsrc[3];
            uint4 q0, q1;
            q0.x = f2bf(wa.x) | ((unsigned)f2bf(wa.y) << 16);
            q0.y = f2bf(wa.z) | ((unsigned)f2bf(wa.w) << 16);
            q0.z = f2bf(wb.x) | ((unsigned)f2bf(wb.y) << 16);
            q0.w = f2bf(wb.z) | ((unsigned)f2bf(wb.w) << 16);
            q1.x = f2bf(wc.x) | ((unsigned)f2bf(wc.y) << 16);
            q1.y = f2bf(wc.z) | ((unsigned)f2bf(wc.w) << 16);
            q1.z = f2bf(wd.x) | ((unsigned)f2bf(wd.y) << 16);
            q1.w = f2bf(wd.z) | ((unsigned)f2bf(wd.w) << 16);
            *(uint4*)&sWs[wco * 32 + wck]     = q0;
            *(uint4*)&sWs[wco * 32 + wck + 8] = q1;
        }
        {
            int ckstart = ck0 + ckb;
            int cc = ckstart / 9;
            int kk = ckstart - cc * 9;
            unsigned int packed[4];
            unsigned short colv[8];
            #pragma unroll
            for (int j = 0; j < 8; ++j) {
                int e = pl9 + kk;
                uint2  id = sIdx[e];
                float4 wv = sW[e];
                const float* xp = xn + ((size_t)cc << 12);
                float v = wv.x * xp[id.x & 0xFFFFu]
                        + wv.y * xp[id.x >> 16]
                        + wv.z * xp[id.y & 0xFFFFu]
                        + wv.w * xp[id.y >> 16];
                colv[j] = f2bf(v);
                ++kk; if (kk == 9) { kk = 0; ++cc; }
            }
            packed[0] = colv[0] | ((unsigned)colv[1] << 16);
            packed[1] = colv[2] | ((unsigned)colv[3] << 16);
            packed[2] = colv[4] | ((unsigned)colv[5] << 16);
            packed[3] = colv[6] | ((unsigned)colv[7] << 16);
            *(uint4*)&sBs[pl * 32 + ckb] = *(uint4*)packed;
        }
        __syncthreads();
        bf16x8 bfr0 = *(const bf16x8*)&sBs[(wp + l15)      * 32 + l4 * 8];
        bf16x8 bfr1 = *(const bf16x8*)&sBs[(wp + 16 + l15) * 32 + l4 * 8];
        #pragma unroll
        for (int m = 0; m < 8; ++m) {
            bf16x8 afr = *(const bf16x8*)&sWs[(wm + m * 16 + l15) * 32 + l4 * 8];
            acc[m][0] = __builtin_amdgcn_mfma_f32_16x16x32_bf16(afr, bfr0, acc[m][0], 0, 0, 0);
            acc[m][1] = __builtin_amdgcn_mfma_f32_16x16x32_bf16(afr, bfr1, acc[m][1], 0, 0, 0);
        }
    }

    float* outn = out + (size_t)n * CO_ * P_;
    #pragma unroll
    for (int m = 0; m < 8; ++m) {
        int co = wm + m * 16 + l4 * 4;
        #pragma unroll
        for (int nn = 0; nn < 2; ++nn) {
            int p = p0 + wp + nn * 16 + l15;
            #pragma unroll
            for (int r = 0; r < 4; ++r) {
                outn[(size_t)(co + r) * P_ + p] = acc[m][nn][r];
            }
        }
    }
}

extern "C" void kernel_launch(void* const* d_in, const int* in_sizes, int n_in,
                              void* d_out, int out_size, void* d_ws, size_t ws_size,
                              hipStream_t stream) {
    const float* x      = (const float*)d_in[0];
    const float* offset = (const float*)d_in[1];
    const float* mask   = (const float*)d_in[2];
    const float* weight = (const float*)d_in[3];
    float* out = (float*)d_out;

    const size_t xT_elems = (size_t)N_ * P_ * C_;            // 8,388,608 ushort
    const size_t Wt_elems = (size_t)CO_ * CK_;               //   589,824 ushort
    const size_t need     = (xT_elems + Wt_elems) * sizeof(unsigned short); // 17,956,864 B

    if (ws_size >= need) {
        unsigned short* xT = (unsigned short*)d_ws;
        unsigned short* Wt = xT + xT_elems;
        prep_fused<<<dim3(TBLK + CO_), dim3(256), 0, stream>>>(x, xT, weight, Wt);
        // grid: 8 n (XCD-pin) x 32 p-tiles = 256 blocks = 1 block/CU, 16 waves
        dcn_main<<<dim3((P_ / BN) * N_), dim3(NTHR), 0, stream>>>(xT, Wt, offset, mask, out);
    } else if (ws_size >= (8u << 20)) {
        dcn_fb<1><<<dim3(P_ / 128, N_), dim3(512), 0, stream>>>(x, offset, mask, weight, out);
    } else {
        dcn_fb<0><<<dim3(P_ / 128, N_), dim3(512), 0, stream>>>(x, offset, mask, weight, out);
    }
}

// Round 21
// 68.477 us; speedup vs baseline: 1.5779x; 1.0213x over previous
//
#include <hip/hip_runtime.h>
#include <hip/hip_bf16.h>
#include <hip/hip_fp16.h>
#include <stdint.h>

#define N_   8
#define C_   256
#define H_   64
#define W_   64
#define CO_  256
#define K_   9
#define HO_  64
#define WO_  64
#define CK_  (C_ * K_)    // 2304
#define P_   (HO_ * WO_)  // 4096

#define BN   128          // p per block
#define BK   64           // ck per K-step (2 MFMA K-slices)
#define NT   36           // K-steps: 9 taps x 4 channel-quarters
#define NTHR 1024         // 16 waves = 4 waves/SIMD
#define TBLK 2048         // transpose blocks in fused pre-pass

typedef __attribute__((ext_vector_type(8))) _Float16 f16x8;
typedef __attribute__((ext_vector_type(4))) float f32x4;

__device__ __forceinline__ unsigned short f2bf(float f) {
    uint32_t u = __builtin_bit_cast(uint32_t, f);
    uint32_t r = (u + 0x7FFFu + ((u >> 16) & 1u)) >> 16;
    return (unsigned short)r;
}
__device__ __forceinline__ float bf2f(unsigned short u) {
    return __builtin_bit_cast(float, (uint32_t)u << 16);
}
__device__ __forceinline__ unsigned short f2h(float f) {
    return __builtin_bit_cast(unsigned short, (_Float16)f);
}

// ================= FAST PATH (needs 17,956,864 B of d_ws) =================

// Fused pre-pass (r20: saved ~2.8us vs two launches): blocks [0,TBLK)
// transpose x[n][c][hw] f32 -> xT[n][hw][c] f16 with 16B stores; blocks
// [TBLK, TBLK+CO_) reorder weight -> Wt[co][k][c] f16.
__global__ __launch_bounds__(256)
void prep_fused(const float* __restrict__ x, unsigned short* __restrict__ xT,
                const float* __restrict__ w, unsigned short* __restrict__ Wt) {
    const int bid = blockIdx.x;
    if (bid < TBLK) {
        const int bx = bid & 63;         // hw tile
        const int by = (bid >> 6) & 3;   // c tile
        const int n  = bid >> 8;         // image
        __shared__ unsigned short t[64][72];   // +8 pad
        const int tx = threadIdx.x & 63;
        const int ty = threadIdx.x >> 6;       // 0..3
        const float* xp = x + ((size_t)n * C_ + by * 64) * P_ + bx * 64;
        #pragma unroll
        for (int i = 0; i < 16; ++i) {
            int c = ty * 16 + i;
            t[c][tx] = f2h(xp[(size_t)c * P_ + tx]);
        }
        __syncthreads();
        const int row = threadIdx.x >> 2;
        const int c0  = (threadIdx.x & 3) * 16;
        unsigned short vals[16];
        #pragma unroll
        for (int j = 0; j < 16; ++j) vals[j] = t[c0 + j][row];
        unsigned short* op = xT + ((size_t)n * P_ + bx * 64 + row) * C_ + by * 64 + c0;
        *(uint4*)op       = *(uint4*)&vals[0];
        *(uint4*)(op + 8) = *(uint4*)&vals[8];
    } else {
        const int co = bid - TBLK;
        const int c  = threadIdx.x;
        const float* src = w + (size_t)co * CK_ + (size_t)c * K_;
        float v[9];
        #pragma unroll
        for (int k = 0; k < 9; ++k) v[k] = src[k];
        #pragma unroll
        for (int k = 0; k < 9; ++k)
            Wt[(size_t)co * CK_ + k * C_ + c] = f2h(v[k]);
    }
}

// Raw-barrier helper: keeps in-flight vmem loads alive across the barrier
// (__syncthreads would force s_waitcnt vmcnt(0) first).
__device__ __forceinline__ void barrier_lgkm_only() {
    __builtin_amdgcn_sched_barrier(0);
    asm volatile("s_waitcnt lgkmcnt(0)" ::: "memory");
    __builtin_amdgcn_s_barrier();
    __builtin_amdgcn_sched_barrier(0);
}

// packed bilinear combine of one u32 (2 f16 channels) per corner
#define COMB(dst, A, B, Cc, D) do {                                   \
    __half2 _v = __hmul2(W0, __builtin_bit_cast(__half2, (A)));       \
    _v = __hfma2(W1, __builtin_bit_cast(__half2, (B)), _v);           \
    _v = __hfma2(W2, __builtin_bit_cast(__half2, (Cc)), _v);          \
    _v = __hfma2(W3, __builtin_bit_cast(__half2, (D)), _v);           \
    (dst) = __builtin_bit_cast(unsigned, _v); } while (0)

// Round 21 dcn_main: r14 EXACT (57.1us measured — best). r20 A/B isolated:
// setprio on this structure = +3.7us regression (all waves same-sequence,
// boosting MFMA starves the staging waves that gate the next barrier) ->
// reverted. r15 (A-from-L2), r16 (ks-split), r17 (conflict-free wstage),
// r18/20 (setprio) all regressed or null; r14's 1-barrier double-buffer with
// counted-vmcnt reg prefetch at 16 waves is the measured optimum.
__global__ __launch_bounds__(NTHR, 4)
void dcn_main(const unsigned short* __restrict__ xT,
              const unsigned short* __restrict__ Wt,
              const float* __restrict__ offset,
              const float* __restrict__ mask,
              float* __restrict__ out) {
    __shared__ uint2 sIdx[BN * K_];               //  9216 B (write-once)
    __shared__ uint4 sWd [BN * K_];               // 18432 B (write-once)
    __shared__ unsigned short sWs[2][CO_ * BK];   // 64 KB double-buffered
    __shared__ unsigned short sBs[2][BN * BK];    // 32 KB double-buffered -> 125952 B

    const int tid = threadIdx.x;
    // XCD-pin: bid%8 = XCD = batch image; per-XCD set ~3.2MB fits 4MB L2.
    const int bid = blockIdx.x;
    const int n   = bid & 7;
    const int p0  = (bid >> 3) * BN;   // 32 p-tiles per image

    for (int e = tid; e < BN * K_; e += NTHR) {
        int pl = e / K_;
        int k  = e - pl * K_;
        int p  = p0 + pl;
        int ho = p >> 6, wo = p & 63;
        float offy = offset[(size_t)((n * 2 * K_ + 2 * k)     * P_) + p];
        float offx = offset[(size_t)((n * 2 * K_ + 2 * k + 1) * P_) + p];
        float m    = mask  [(size_t)((n * K_ + k) * P_) + p];
        float py = (float)(k / 3 + ho - 1) + offy;
        float px = (float)(k % 3 + wo - 1) + offx;
        float y0f = floorf(py), x0f = floorf(px);
        float ly = py - y0f,   lx = px - x0f;
        int y0 = (int)y0f, x0 = (int)x0f;
        int y1 = y0 + 1,   x1 = x0 + 1;
        bool vy0 = (y0 >= 0) & (y0 < H_);
        bool vy1 = (y1 >= 0) & (y1 < H_);
        bool vx0 = (x0 >= 0) & (x0 < W_);
        bool vx1 = (x1 >= 0) & (x1 < W_);
        float w00 = (1.f - ly) * (1.f - lx) * m * ((vy0 & vx0) ? 1.f : 0.f);
        float w01 = (1.f - ly) * lx         * m * ((vy0 & vx1) ? 1.f : 0.f);
        float w10 = ly * (1.f - lx)         * m * ((vy1 & vx0) ? 1.f : 0.f);
        float w11 = ly * lx                 * m * ((vy1 & vx1) ? 1.f : 0.f);
        unsigned int cy0 = (unsigned)min(max(y0, 0), H_ - 1);
        unsigned int cy1 = (unsigned)min(max(y1, 0), H_ - 1);
        unsigned int cx0 = (unsigned)min(max(x0, 0), W_ - 1);
        unsigned int cx1 = (unsigned)min(max(x1, 0), W_ - 1);
        sIdx[e] = make_uint2((cy0 * W_ + cx0) | ((cy0 * W_ + cx1) << 16),
                             (cy1 * W_ + cx0) | ((cy1 * W_ + cx1) << 16));
        sWd[e] = make_uint4((unsigned)f2h(w00) * 0x10001u,
                            (unsigned)f2h(w01) * 0x10001u,
                            (unsigned)f2h(w10) * 0x10001u,
                            (unsigned)f2h(w11) * 0x10001u);
    }
    __syncthreads();   // params visible before prefetch(0) reads sIdx

    const unsigned short* xTn = xT + (size_t)n * P_ * C_;

    // ---- roles (identical to r14) ----
    const int spl = tid >> 3;                 // 0..127
    const int cs  = tid & 7;                  // channel slot (8 f16 = 16B)
    const int boff = spl * 128 + ((cs ^ (spl & 7)) << 4);
    const int wco  = tid >> 2;                // 0..255
    const int wsl  = tid & 3;                 // slots wsl and wsl+4
    const int wswz = wco & 7;
    const int woff = wco * 128;
    const unsigned short* wsrcbase = Wt + (size_t)wco * CK_ + wsl * 8;

    const int lane = tid & 63;
    const int wid  = tid >> 6;                // 0..15
    const int wm   = (wid & 7) * 32;          // 8 co-groups
    const int wp   = (wid >> 3) * 64;         // 2 p-groups
    const int l15  = lane & 15;
    const int l4   = lane >> 4;
    const int slA  = l4 ^ (l15 & 7);          // ks=0 slot; ks=1 -> ^4

    f32x4 acc[2][4] = {};

    // prefetch registers (one tile ahead, in flight across the barrier)
    uint4 qa, qb, qc, qd;    // 4 corners x 8 f16
    uint4 wq0, wq1;          // 2x 16B of weight row

#define PREF(TT) {                                                        \
        const int kn  = (TT) >> 2;                                        \
        const int c0n = ((TT) & 3) * 64;                                  \
        const unsigned short* ws = wsrcbase + kn * C_ + c0n;              \
        wq0 = *(const uint4*)(ws);                                        \
        wq1 = *(const uint4*)(ws + 32);                                   \
        uint2 id = sIdx[spl * K_ + kn];                                   \
        const unsigned short* base = xTn + c0n + cs * 8;                  \
        qa = *(const uint4*)(base + ((size_t)(id.x & 0xFFFFu) << 8));     \
        qb = *(const uint4*)(base + ((size_t)(id.x >> 16)     << 8));     \
        qc = *(const uint4*)(base + ((size_t)(id.y & 0xFFFFu) << 8));     \
        qd = *(const uint4*)(base + ((size_t)(id.y >> 16)     << 8));     \
    }

#define STAGE(TT, WB, BB) {                                               \
        char* wrB = (char*)(WB) + woff;                                   \
        *(uint4*)(wrB + ((wsl       ^ wswz) << 4)) = wq0;                 \
        *(uint4*)(wrB + (((wsl + 4) ^ wswz) << 4)) = wq1;                 \
        uint4 wv = sWd[spl * K_ + ((TT) >> 2)];                           \
        __half2 W0 = __builtin_bit_cast(__half2, wv.x);                   \
        __half2 W1 = __builtin_bit_cast(__half2, wv.y);                   \
        __half2 W2 = __builtin_bit_cast(__half2, wv.z);                   \
        __half2 W3 = __builtin_bit_cast(__half2, wv.w);                   \
        uint4 r;                                                          \
        COMB(r.x, qa.x, qb.x, qc.x, qd.x);                                \
        COMB(r.y, qa.y, qb.y, qc.y, qd.y);                                \
        COMB(r.z, qa.z, qb.z, qc.z, qd.z);                                \
        COMB(r.w, qa.w, qb.w, qc.w, qd.w);                                \
        *(uint4*)((char*)(BB) + boff) = r;                                \
    }

    // ---- prologue: tile 0 -> regs -> buf0; tile 1 -> regs ----
    PREF(0)
    STAGE(0, sWs[0], sBs[0])
    PREF(1)

    for (int t = 0; t < NT; ++t) {
        const int br = t & 1;
        const char* wR = (const char*)sWs[br];
        const char* bR = (const char*)sBs[br];

        // single barrier: buf[br] writes (last iter) visible; buf[br^1] reads
        // (last iter's MFMA) complete. In-flight global loads survive.
        barrier_lgkm_only();

        // ks=0 fragment reads (in regs across the stage)
        f16x8 A0, A1, B0, B1, B2, B3;
        {
            const int sl = slA;
            B0 = *(const f16x8*)(bR + (wp      + l15) * 128 + (sl << 4));
            B1 = *(const f16x8*)(bR + (wp + 16 + l15) * 128 + (sl << 4));
            B2 = *(const f16x8*)(bR + (wp + 32 + l15) * 128 + (sl << 4));
            B3 = *(const f16x8*)(bR + (wp + 48 + l15) * 128 + (sl << 4));
            A0 = *(const f16x8*)(wR + (wm      + l15) * 128 + (sl << 4));
            A1 = *(const f16x8*)(wR + (wm + 16 + l15) * 128 + (sl << 4));
        }

        // stage tile t+1 into the write buffer (different buffer -> no
        // second barrier); then issue tile t+2's global loads
        if (t + 1 < NT) {
            if (br) { STAGE(t + 1, sWs[0], sBs[0]) }
            else    { STAGE(t + 1, sWs[1], sBs[1]) }
            if (t + 2 < NT) PREF(t + 2)
        }

        // MFMA ks=0 (co-schedules with the ds_writes above)
        acc[0][0] = __builtin_amdgcn_mfma_f32_16x16x32_f16(A0, B0, acc[0][0], 0, 0, 0);
        acc[0][1] = __builtin_amdgcn_mfma_f32_16x16x32_f16(A0, B1, acc[0][1], 0, 0, 0);
        acc[0][2] = __builtin_amdgcn_mfma_f32_16x16x32_f16(A0, B2, acc[0][2], 0, 0, 0);
        acc[0][3] = __builtin_amdgcn_mfma_f32_16x16x32_f16(A0, B3, acc[0][3], 0, 0, 0);
        acc[1][0] = __builtin_amdgcn_mfma_f32_16x16x32_f16(A1, B0, acc[1][0], 0, 0, 0);
        acc[1][1] = __builtin_amdgcn_mfma_f32_16x16x32_f16(A1, B1, acc[1][1], 0, 0, 0);
        acc[1][2] = __builtin_amdgcn_mfma_f32_16x16x32_f16(A1, B2, acc[1][2], 0, 0, 0);
        acc[1][3] = __builtin_amdgcn_mfma_f32_16x16x32_f16(A1, B3, acc[1][3], 0, 0, 0);

        // ks=1 fragment reads + MFMA
        {
            const int sl = slA ^ 4;
            B0 = *(const f16x8*)(bR + (wp      + l15) * 128 + (sl << 4));
            B1 = *(const f16x8*)(bR + (wp + 16 + l15) * 128 + (sl << 4));
            B2 = *(const f16x8*)(bR + (wp + 32 + l15) * 128 + (sl << 4));
            B3 = *(const f16x8*)(bR + (wp + 48 + l15) * 128 + (sl << 4));
            A0 = *(const f16x8*)(wR + (wm      + l15) * 128 + (sl << 4));
            A1 = *(const f16x8*)(wR + (wm + 16 + l15) * 128 + (sl << 4));
        }
        acc[0][0] = __builtin_amdgcn_mfma_f32_16x16x32_f16(A0, B0, acc[0][0], 0, 0, 0);
        acc[0][1] = __builtin_amdgcn_mfma_f32_16x16x32_f16(A0, B1, acc[0][1], 0, 0, 0);
        acc[0][2] = __builtin_amdgcn_mfma_f32_16x16x32_f16(A0, B2, acc[0][2], 0, 0, 0);
        acc[0][3] = __builtin_amdgcn_mfma_f32_16x16x32_f16(A0, B3, acc[0][3], 0, 0, 0);
        acc[1][0] = __builtin_amdgcn_mfma_f32_16x16x32_f16(A1, B0, acc[1][0], 0, 0, 0);
        acc[1][1] = __builtin_amdgcn_mfma_f32_16x16x32_f16(A1, B1, acc[1][1], 0, 0, 0);
        acc[1][2] = __builtin_amdgcn_mfma_f32_16x16x32_f16(A1, B2, acc[1][2], 0, 0, 0);
        acc[1][3] = __builtin_amdgcn_mfma_f32_16x16x32_f16(A1, B3, acc[1][3], 0, 0, 0);
    }
#undef PREF
#undef STAGE

    float* outn = out + (size_t)n * CO_ * P_;
    #pragma unroll
    for (int m = 0; m < 2; ++m) {
        int co = wm + m * 16 + l4 * 4;
        #pragma unroll
        for (int nn = 0; nn < 4; ++nn) {
            int p = p0 + wp + nn * 16 + l15;
            #pragma unroll
            for (int r = 0; r < 4; ++r) {
                outn[(size_t)(co + r) * P_ + p] = acc[m][nn][r];
            }
        }
    }
}

// ================= FALLBACK (round-2 kernel, zero scratch, proven pass) =================
template <int TAG>
__global__ __launch_bounds__(512, 2)
void dcn_fb(const float* __restrict__ x,
            const float* __restrict__ offset,
            const float* __restrict__ mask,
            const float* __restrict__ weight,
            float* __restrict__ out) {
    typedef __attribute__((ext_vector_type(8))) short bf16x8;
    __shared__ uint2  sIdx[128 * K_];
    __shared__ float4 sW  [128 * K_];
    __shared__ unsigned short sWs[CO_ * 32];
    __shared__ unsigned short sBs[128 * 32];

    const int tid = threadIdx.x;
    const int n  = blockIdx.y;
    const int p0 = blockIdx.x * 128;

    for (int e = tid; e < 128 * K_; e += 512) {
        int pl = e / K_;
        int k  = e - pl * K_;
        int p  = p0 + pl;
        int ho = p >> 6, wo = p & 63;
        float offy = offset[(size_t)((n * 2 * K_ + 2 * k)     * P_) + p];
        float offx = offset[(size_t)((n * 2 * K_ + 2 * k + 1) * P_) + p];
        float m    = mask  [(size_t)((n * K_ + k) * P_) + p];
        float py = (float)(k / 3 + ho - 1) + offy;
        float px = (float)(k % 3 + wo - 1) + offx;
        float y0f = floorf(py), x0f = floorf(px);
        float ly = py - y0f,   lx = px - x0f;
        int y0 = (int)y0f, x0 = (int)x0f;
        int y1 = y0 + 1,   x1 = x0 + 1;
        bool vy0 = (y0 >= 0) & (y0 < H_);
        bool vy1 = (y1 >= 0) & (y1 < H_);
        bool vx0 = (x0 >= 0) & (x0 < W_);
        bool vx1 = (x1 >= 0) & (x1 < W_);
        float w00 = (1.f - ly) * (1.f - lx) * m * ((vy0 & vx0) ? 1.f : 0.f);
        float w01 = (1.f - ly) * lx         * m * ((vy0 & vx1) ? 1.f : 0.f);
        float w10 = ly * (1.f - lx)         * m * ((vy1 & vx0) ? 1.f : 0.f);
        float w11 = ly * lx                 * m * ((vy1 & vx1) ? 1.f : 0.f);
        unsigned int cy0 = (unsigned)min(max(y0, 0), H_ - 1);
        unsigned int cy1 = (unsigned)min(max(y1, 0), H_ - 1);
        unsigned int cx0 = (unsigned)min(max(x0, 0), W_ - 1);
        unsigned int cx1 = (unsigned)min(max(x1, 0), W_ - 1);
        sIdx[e] = make_uint2((cy0 * W_ + cx0) | ((cy0 * W_ + cx1) << 16),
                             (cy1 * W_ + cx0) | ((cy1 * W_ + cx1) << 16));
        sW[e]   = make_float4(w00, w01, w10, w11);
    }

    const float* xn = x + (size_t)n * C_ * P_;
    const int pl   = tid >> 2;
    const int pl9  = pl * K_;
    const int ckb  = (tid & 3) * 8;
    const int wco  = tid >> 1;
    const int wck  = (tid & 1) * 16;

    const int lane = tid & 63;
    const int wid  = tid >> 6;
    const int wm   = (wid & 1) * 128;
    const int wp   = (wid >> 1) * 32;
    const int l15  = lane & 15;
    const int l4   = lane >> 4;

    f32x4 acc[8][2] = {};

    for (int ck0 = 0; ck0 < CK_; ck0 += 32) {
        __syncthreads();
        {
            const float4* wsrc = (const float4*)(weight + (size_t)wco * CK_ + ck0 + wck);
            float4 wa = wsrc[0], wb = wsrc[1], wc = wsrc[2], wd = wsrc[3];
            uint4 q0, q1;
            q0.x = f2bf(wa.x) | ((unsigned)f2bf(wa.y) << 16);
            q0.y = f2bf(wa.z) | ((unsigned)f2bf(wa.w) << 16);
            q0.z = f2bf(wb.x) | ((unsigned)f2bf(wb.y) << 16);
            q0.w = f2bf(wb.z) | ((unsigned)f2bf(wb.w) << 16);
            q1.x = f2bf(wc.x) | ((unsigned)f2bf(wc.y) << 16);
            q1.y = f2bf(wc.z) | ((unsigned)f2bf(wc.w) << 16);
            q1.z = f2bf(wd.x) | ((unsigned)f2bf(wd.y) << 16);
            q1.w = f2bf(wd.z) | ((unsigned)f2bf(wd.w) << 16);
            *(uint4*)&sWs[wco * 32 + wck]     = q0;
            *(uint4*)&sWs[wco * 32 + wck + 8] = q1;
        }
        {
            int ckstart = ck0 + ckb;
            int cc = ckstart / 9;
            int kk = ckstart - cc * 9;
            unsigned int packed[4];
            unsigned short colv[8];
            #pragma unroll
            for (int j = 0; j < 8; ++j) {
                int e = pl9 + kk;
                uint2  id = sIdx[e];
                float4 wv = sW[e];
                const float* xp = xn + ((size_t)cc << 12);
                float v = wv.x * xp[id.x & 0xFFFFu]
                        + wv.y * xp[id.x >> 16]
                        + wv.z * xp[id.y & 0xFFFFu]
                        + wv.w * xp[id.y >> 16];
                colv[j] = f2bf(v);
                ++kk; if (kk == 9) { kk = 0; ++cc; }
            }
            packed[0] = colv[0] | ((unsigned)colv[1] << 16);
            packed[1] = colv[2] | ((unsigned)colv[3] << 16);
            packed[2] = colv[4] | ((unsigned)colv[5] << 16);
            packed[3] = colv[6] | ((unsigned)colv[7] << 16);
            *(uint4*)&sBs[pl * 32 + ckb] = *(uint4*)packed;
        }
        __syncthreads();
        bf16x8 bfr0 = *(const bf16x8*)&sBs[(wp + l15)      * 32 + l4 * 8];
        bf16x8 bfr1 = *(const bf16x8*)&sBs[(wp + 16 + l15) * 32 + l4 * 8];
        #pragma unroll
        for (int m = 0; m < 8; ++m) {
            bf16x8 afr = *(const bf16x8*)&sWs[(wm + m * 16 + l15) * 32 + l4 * 8];
            acc[m][0] = __builtin_amdgcn_mfma_f32_16x16x32_bf16(afr, bfr0, acc[m][0], 0, 0, 0);
            acc[m][1] = __builtin_amdgcn_mfma_f32_16x16x32_bf16(afr, bfr1, acc[m][1], 0, 0, 0);
        }
    }

    float* outn = out + (size_t)n * CO_ * P_;
    #pragma unroll
    for (int m = 0; m < 8; ++m) {
        int co = wm + m * 16 + l4 * 4;
        #pragma unroll
        for (int nn = 0; nn < 2; ++nn) {
            int p = p0 + wp + nn * 16 + l15;
            #pragma unroll
            for (int r = 0; r < 4; ++r) {
                outn[(size_t)(co + r) * P_ + p] = acc[m][nn][r];
            }
        }
    }
}

extern "C" void kernel_launch(void* const* d_in, const int* in_sizes, int n_in,
                              void* d_out, int out_size, void* d_ws, size_t ws_size,
                              hipStream_t stream) {
    const float* x      = (const float*)d_in[0];
    const float* offset = (const float*)d_in[1];
    const float* mask   = (const float*)d_in[2];
    const float* weight = (const float*)d_in[3];
    float* out = (float*)d_out;

    const size_t xT_elems = (size_t)N_ * P_ * C_;            // 8,388,608 ushort
    const size_t Wt_elems = (size_t)CO_ * CK_;               //   589,824 ushort
    const size_t need     = (xT_elems + Wt_elems) * sizeof(unsigned short); // 17,956,864 B

    if (ws_size >= need) {
        unsigned short* xT = (unsigned short*)d_ws;
        unsigned short* Wt = xT + xT_elems;
        prep_fused<<<dim3(TBLK + CO_), dim3(256), 0, stream>>>(x, xT, weight, Wt);
        // grid: 8 n (XCD-pin) x 32 p-tiles = 256 blocks = 1 block/CU, 16 waves
        dcn_main<<<dim3((P_ / BN) * N_), dim3(NTHR), 0, stream>>>(xT, Wt, offset, mask, out);
    } else if (ws_size >= (8u << 20)) {
        dcn_fb<1><<<dim3(P_ / 128, N_), dim3(512), 0, stream>>>(x, offset, mask, weight, out);
    } else {
        dcn_fb<0><<<dim3(P_ / 128, N_), dim3(512), 0, stream>>>(x, offset, mask, weight, out);
    }
}